// Round 6
// baseline (212.818 us; speedup 1.0000x reference)
//
#include <hip/hip_runtime.h>
#include <math.h>

#define BB  4
#define SS  1024
#define DD  512
#define HH  8
#define DHD 64
#define PL  2097152      // elements per Q/K/V/Ob plane (also B*S*D)
#define WPL 262144       // elements per W plane

constexpr float LN_EPS = 1e-5f;

using half4 = __attribute__((ext_vector_type(4))) _Float16;
using half8 = __attribute__((ext_vector_type(8))) _Float16;
using f32x4 = __attribute__((ext_vector_type(4))) float;

__device__ __forceinline__ half8 negh(half8 a) {
    union { half8 h; unsigned int u[4]; } t;
    t.h = a;
    #pragma unroll
    for (int i = 0; i < 4; ++i) t.u[i] ^= 0x80008000u;
    return t.h;
}
// 64-wide swizzled rows (XOR (row&7)<<3, 8-half granules): conflict-free b128
__device__ __forceinline__ half8 ldh64(const unsigned short* p, int row, int col) {
    return *(const half8*)(p + row * 64 + (col ^ ((row & 7) << 3)));
}
// packed f32x2 -> f16x2 (RTZ), as raw u32
__device__ __forceinline__ unsigned int cvtpk(float a, float b) {
    union { decltype(__builtin_amdgcn_cvt_pkrtz(0.f, 0.f)) v; unsigned int u; } t;
    t.v = __builtin_amdgcn_cvt_pkrtz(a, b);
    return t.u;
}
// native v_exp_f32 (2^x) — NOT the precise OCML exp2f path
__device__ __forceinline__ float ex2(float x) { return __builtin_amdgcn_exp2f(x); }
#define MFMA16(acc, a, b) acc = __builtin_amdgcn_mfma_f32_16x16x32_f16(a, b, acc, 0, 0, 0)

// ---------------------------------------------------------------------------
// Kernel 0: fp32 complex -> fp16 r/i planes, TILE-BLOCKED layout:
// plane stored as [m/128][d/64][128][64] so proj's K-step strips are 16KB
// contiguous (HBM-stream friendly) instead of 128B-at-1KB-stride.
// ---------------------------------------------------------------------------
__global__ __launch_bounds__(256)
void cvt_kernel(const float2* __restrict__ s0, const float2* __restrict__ s1,
                const float2* __restrict__ s2, unsigned short* __restrict__ dst,
                int planeElems) {
    const int z = blockIdx.y;
    const float2* src = z == 0 ? s0 : (z == 1 ? s1 : s2);
    unsigned short* base = dst + (size_t)z * 2 * planeElems;
    const int idx = (blockIdx.x * 256 + threadIdx.x) * 2;   // complex index (even)
    float4 t = *(const float4*)(src + idx);
    const int m = idx >> 9;          // row
    const int d = idx & 511;         // col (even)
    const int ob = (((m >> 7) << 3) + (d >> 6)) * 8192 + ((m & 127) << 6) + (d & 63);
    union { _Float16 h[2]; unsigned int u; } r, i;
    r.h[0] = (_Float16)t.x; r.h[1] = (_Float16)t.z;
    i.h[0] = (_Float16)t.y; i.h[1] = (_Float16)t.w;
    *(unsigned int*)(base + ob) = r.u;
    *(unsigned int*)(base + planeElems + ob) = i.u;
}

// ---------------------------------------------------------------------------
// Kernel 1: complex projection — round-6: 8 waves (512 thr), same 128x128
// tile. Wave-tile 64x32 (wm=w>>2, we=w&3): per-SIMD wave count doubles at
// equal residency (the round-5 counters showed ~1 wave/SIMD: every ds->MFMA
// dep and barrier drain exposed). acc halves to 64 VGPR. Staging: wave w
// DMAs plane (w>>1), half (w&1) — 8 x 1KB each; same blocked-layout
// source-side swizzle.
// ---------------------------------------------------------------------------
__global__ __launch_bounds__(512, 2)
void proj_kernel(const unsigned short* __restrict__ XP,
                 const unsigned short* __restrict__ WP,
                 const float2* __restrict__ bq, const float2* __restrict__ bk,
                 const float2* __restrict__ bv,
                 unsigned short* __restrict__ QG, unsigned short* __restrict__ KG,
                 unsigned short* __restrict__ VG) {
    const unsigned short* XR = XP + (size_t)blockIdx.z * 2 * PL;
    const unsigned short* XI = XR + PL;
    const unsigned short* WRp = WP + (size_t)blockIdx.z * 2 * WPL;
    const unsigned short* WIp = WRp + WPL;
    const float2* bias; unsigned short* outP;
    if (blockIdx.z == 0)      { bias = bq; outP = QG; }
    else if (blockIdx.z == 1) { bias = bk; outP = KG; }
    else                      { bias = bv; outP = VG; }
    const bool isV = (blockIdx.z == 2);

    __shared__ __align__(16) unsigned short Xs[2][128 * 64];
    __shared__ __align__(16) unsigned short Ws[2][128 * 64];

    const int tid  = threadIdx.x;
    const int w    = tid >> 6;               // 0..7
    const int lane = tid & 63;
    const int quad = lane >> 4;
    const int l15  = lane & 15;
    const int wm   = w >> 2;                 // m half (64 rows)
    const int we   = w & 3;                  // e quarter (32 rows)
    const int m0   = blockIdx.x * 128;
    const int e0   = blockIdx.y * 128;

    // ---- staging: wave w owns plane (w>>1), half (w&1): 8 x 1KB DMA/step ----
    const int srow = lane >> 3;              // 0..7
    const int sg   = lane & 7;               // granule within row
    const int pp   = w >> 1;                 // 0..3: Xr,Xi,Wr,Wi
    const int hf   = w & 1;                  // row half (64 rows)
    const unsigned short* gplane;
    unsigned short* lb;
    int row0;
    if (pp == 0)      { gplane = XR;  row0 = m0; lb = &Xs[0][0]; }
    else if (pp == 1) { gplane = XI;  row0 = m0; lb = &Xs[1][0]; }
    else if (pp == 2) { gplane = WRp; row0 = e0; lb = &Ws[0][0]; }
    else              { gplane = WIp; row0 = e0; lb = &Ws[1][0]; }
    const unsigned short* gs = gplane + (size_t)row0 * DD
                             + (hf * 64 + srow) * 64 + ((sg ^ srow) << 3);
    lb += hf * 4096;

    f32x4 Sr[4][2], Si[4][2];                // [mf][ef]
    #pragma unroll
    for (int a = 0; a < 4; ++a)
        #pragma unroll
        for (int c = 0; c < 2; ++c) { Sr[a][c] = (f32x4)0.f; Si[a][c] = (f32x4)0.f; }

    for (int s = 0; s < 8; ++s) {
        if (s) __syncthreads();              // prev compute done before overwrite
        const unsigned short* _g = gs + (size_t)s * 8192;   // next 16KB d-block
        #pragma unroll
        for (int j = 0; j < 8; ++j)
            __builtin_amdgcn_global_load_lds(
                (const __attribute__((address_space(1))) void*)(_g + j * 512),
                (__attribute__((address_space(3))) void*)(lb + j * 512),
                16, 0, 0);
        __syncthreads();                     // vmcnt drain -> tile ready

        #pragma unroll
        for (int kc = 0; kc < 2; ++kc) {
            const int dl = kc * 32 + quad * 8;
            half8 xr[4], xi[4];
            #pragma unroll
            for (int mf = 0; mf < 4; ++mf) {
                const int mr = wm * 64 + mf * 16 + l15;
                xr[mf] = ldh64(Xs[0], mr, dl);
                xi[mf] = ldh64(Xs[1], mr, dl);
            }
            #pragma unroll
            for (int ef = 0; ef < 2; ++ef) {
                const int er = we * 32 + ef * 16 + l15;
                half8 wr  = ldh64(Ws[0], er, dl);
                half8 wi  = ldh64(Ws[1], er, dl);
                half8 wmi = negh(wi);
                #pragma unroll
                for (int mf = 0; mf < 4; ++mf) {
                    MFMA16(Sr[mf][ef], xr[mf], wr);    // Xr.Wr
                    MFMA16(Sr[mf][ef], xi[mf], wmi);   // -Xi.Wi
                    MFMA16(Si[mf][ef], xr[mf], wi);    // Xr.Wi
                    MFMA16(Si[mf][ef], xi[mf], wr);    // Xi.Wr
                }
            }
        }
    }

    // ---- epilogue: + bias, fp16, write planes (V transposed) ----
    #pragma unroll
    for (int ef = 0; ef < 2; ++ef) {
        const int eg  = e0 + we * 32 + ef * 16 + l15;   // global out column
        const int hh  = eg >> 6;                         // head
        const int col = eg & 63;
        float2 bb = bias[eg];
        #pragma unroll
        for (int mf = 0; mf < 4; ++mf) {
            #pragma unroll
            for (int reg = 0; reg < 4; ++reg) {
                int m = m0 + wm * 64 + mf * 16 + quad * 4 + reg;
                int bidx = m >> 10;
                int sidx = m & 1023;
                int bh = bidx * HH + hh;
                union { _Float16 h; unsigned short u; } cr, ci;
                cr.h = (_Float16)(Sr[mf][ef][reg] + bb.x);
                ci.h = (_Float16)(Si[mf][ef][reg] + bb.y);
                size_t o = isV ? ((size_t)bh * DHD + col) * SS + sidx
                               : ((size_t)bh * SS + sidx) * DHD + col;
                outP[0 * PL + o] = cr.u;
                outP[1 * PL + o] = ci.u;
            }
        }
    }
}

// ---------------------------------------------------------------------------
// Kernel 2: fp16 MFMA flash attention, S^T formulation.
// Round-6: counted-vmcnt sync (T4). Raw s_barrier + role-targeted waits:
//   SYNC1: all waves lgkmcnt(0) (publish Ps); V-waves vmcnt(0) (V(t) landed).
//          K-waves keep their 8 K(t+1) DMAs in flight across the barrier.
//   SYNC2: K-waves vmcnt(0) (K(t+1) landed, published by barrier for next
//          iter's scores). No full drains mid-loop.
// ---------------------------------------------------------------------------
#define AWID 72
__global__ __launch_bounds__(256, 2)
void attn_kernel(const unsigned short* __restrict__ QG, const unsigned short* __restrict__ KG,
                 const unsigned short* __restrict__ VG,
                 unsigned short* __restrict__ ObR, unsigned short* __restrict__ ObI) {
    __shared__ __align__(16) unsigned short Ks[2][2][64 * 64]; // [buf][r,i][k][d] swizzled
    __shared__ __align__(16) unsigned short Vt[2][64 * 64];    // [r,i][d][k] swizzled
    __shared__ __align__(16) unsigned short Ps[2][64 * AWID];  // [r,i][q][k]
    __shared__ float lbuf[2][2][64];                           // [plane][k-half][q]

    const int n   = blockIdx.x;
    const int bh  = (n & 7) * 4 + (n >> 7);       // XCD-local bh group
    const int q0  = ((n >> 3) & 15) * 64;
    const int b   = bh >> 3;
    const int h   = bh & 7;

    const int tid  = threadIdx.x;
    const int w    = tid >> 6;
    const int lane = tid & 63;
    const int quad = lane >> 4;
    const int l15  = lane & 15;
    const int sw   = w & 1;        // q-half (both phases)
    const int tw   = w >> 1;       // k-half (scores) / d-half (PV)

    // ---- DMA staging setup: waves 0,1 own K planes; waves 2,3 own V planes ----
    const int srow = lane >> 3;    // 0..7 (row within 8-row DMA group)
    const int sg   = lane & 7;     // dest granule; source granule = sg^srow
    const bool isK = (w < 2);
    const unsigned short* bpK = nullptr;
    const unsigned short* bpV = nullptr;
    unsigned short* ldV = nullptr;
    if (isK) {
        bpK = KG + (size_t)w * PL + (size_t)bh * SS * DHD + srow * DHD + ((sg ^ srow) << 3);
    } else {
        bpV = VG + (size_t)(w - 2) * PL + (size_t)bh * DHD * SS + srow * SS + ((sg ^ srow) << 3);
        ldV = &Vt[w - 2][0];
    }

#define GLD(SRC, DST) __builtin_amdgcn_global_load_lds( \
        (const __attribute__((address_space(1))) void*)(SRC), \
        (__attribute__((address_space(3))) void*)(DST), 16, 0, 0)

    // ---- prologue: stage K(0) into buf0 ----
    if (isK) {
        unsigned short* ld = &Ks[0][w][0];
        #pragma unroll
        for (int j = 0; j < 8; ++j) GLD(bpK + j * 8 * DHD, ld + j * 512);
    }

    // Q in B-layout registers: lane = q col, quad*8+j = d within 32-window
    half8 qfr[2][2], qfi[2][2], qfmi[2][2];       // [qt][kc]
    #pragma unroll
    for (int qt = 0; qt < 2; ++qt)
        #pragma unroll
        for (int kc = 0; kc < 2; ++kc) {
            size_t qa = ((size_t)bh * SS + q0 + sw * 32 + qt * 16 + l15) * DHD + kc * 32 + quad * 8;
            qfr[qt][kc]  = *(const half8*)(QG + qa);
            qfi[qt][kc]  = *(const half8*)(QG + PL + qa);
            qfmi[qt][kc] = negh(qfi[qt][kc]);
        }

    f32x4 acc[2][2][4];            // [qt][dt][PrVr,PrVi,PiVr,PiVi]
    #pragma unroll
    for (int qt = 0; qt < 2; ++qt)
        #pragma unroll
        for (int dt = 0; dt < 2; ++dt)
            #pragma unroll
            for (int p = 0; p < 4; ++p) acc[qt][dt][p] = (f32x4)0.f;
    float lacc[2][2] = {{0.f, 0.f}, {0.f, 0.f}};  // [qt][plane]

    constexpr float EC = 0.18033688011112042f;    // log2(e)/8

    __syncthreads();               // K(0) staged (full drain once, prologue)

    // double-buffer pointer sets (swapped per iteration; register moves only)
    const unsigned short* Kr_c = &Ks[0][0][0];
    const unsigned short* Ki_c = &Ks[0][1][0];
    const unsigned short* Kr_n = &Ks[1][0][0];
    const unsigned short* Ki_n = &Ks[1][1][0];
    unsigned short* kst_nxt = isK ? &Ks[1][w][0] : nullptr;
    unsigned short* kst_alt = isK ? &Ks[0][w][0] : nullptr;

    for (int t = 0; t < 16; ++t) {
        // ---- issue prefetch: K(t+1) -> next buf (waves 0,1); V(t) (waves 2,3)
        if (isK) {
            if (t < 15) {
                const unsigned short* g = bpK + (size_t)(t + 1) * 64 * DHD;
                #pragma unroll
                for (int j = 0; j < 8; ++j) GLD(g + j * 8 * DHD, kst_nxt + j * 512);
            }
        } else {
            const unsigned short* g = bpV + (size_t)t * 64;
            #pragma unroll
            for (int j = 0; j < 8; ++j) GLD(g + j * 8 * SS, ldV + j * 512);
        }

        // ---- scores: S^T[k32][q32] from current K buffer ----
        f32x4 Sr[2][2], Si[2][2];   // [kt2][qt]
        #pragma unroll
        for (int a = 0; a < 2; ++a)
            #pragma unroll
            for (int c = 0; c < 2; ++c) { Sr[a][c] = (f32x4)0.f; Si[a][c] = (f32x4)0.f; }
        #pragma unroll
        for (int kc = 0; kc < 2; ++kc) {
            const int dl = kc * 32 + quad * 8;
            #pragma unroll
            for (int kt2 = 0; kt2 < 2; ++kt2) {
                const int krow = tw * 32 + kt2 * 16 + l15;
                half8 akr = ldh64(Kr_c, krow, dl);
                half8 aki = ldh64(Ki_c, krow, dl);
                #pragma unroll
                for (int qt = 0; qt < 2; ++qt) {
                    MFMA16(Sr[kt2][qt], akr, qfr[qt][kc]);    // K_r . Q_r
                    MFMA16(Sr[kt2][qt], aki, qfmi[qt][kc]);   // -K_i . Q_i
                    MFMA16(Si[kt2][qt], aki, qfr[qt][kc]);    // K_i . Q_r
                    MFMA16(Si[kt2][qt], akr, qfi[qt][kc]);    // K_r . Q_i
                }
            }
        }

        // ---- exp -> P (packed b64, q-major), l partial per lane ----
        #pragma unroll
        for (int kt2 = 0; kt2 < 2; ++kt2)
            #pragma unroll
            for (int qt = 0; qt < 2; ++qt) {
                float er0 = ex2(Sr[kt2][qt][0] * EC), er1 = ex2(Sr[kt2][qt][1] * EC);
                float er2 = ex2(Sr[kt2][qt][2] * EC), er3 = ex2(Sr[kt2][qt][3] * EC);
                float ei0 = ex2(Si[kt2][qt][0] * EC), ei1 = ex2(Si[kt2][qt][1] * EC);
                float ei2 = ex2(Si[kt2][qt][2] * EC), ei3 = ex2(Si[kt2][qt][3] * EC);
                lacc[qt][0] += (er0 + er1) + (er2 + er3);
                lacc[qt][1] += (ei0 + ei1) + (ei2 + ei3);
                const int qrow = sw * 32 + qt * 16 + l15;
                const int kcol = tw * 32 + kt2 * 16 + quad * 4;
                uint2 pr, pi;
                pr.x = cvtpk(er0, er1); pr.y = cvtpk(er2, er3);
                pi.x = cvtpk(ei0, ei1); pi.y = cvtpk(ei2, ei3);
                *(uint2*)&Ps[0][qrow * AWID + kcol] = pr;
                *(uint2*)&Ps[1][qrow * AWID + kcol] = pi;
            }

        // ---- SYNC1: publish Ps (lgkm); V-waves land V(t); K prefetch stays
        //      in flight across the barrier (counted-vmcnt, T4). ----
        asm volatile("s_waitcnt lgkmcnt(0)" ::: "memory");
        if (!isK) asm volatile("s_waitcnt vmcnt(0)" ::: "memory");
        __builtin_amdgcn_s_barrier();
        asm volatile("" ::: "memory");

        // ---- PV: out tile q32 (sw) x d32 (tw), k64 accumulation ----
        #pragma unroll
        for (int kc = 0; kc < 2; ++kc) {
            half8 ap[2][2];   // [qt][plane]
            #pragma unroll
            for (int qt = 0; qt < 2; ++qt) {
                const int qrow = sw * 32 + qt * 16 + l15;
                ap[qt][0] = *(const half8*)&Ps[0][qrow * AWID + kc * 32 + quad * 8];
                ap[qt][1] = *(const half8*)&Ps[1][qrow * AWID + kc * 32 + quad * 8];
            }
            #pragma unroll
            for (int dt = 0; dt < 2; ++dt) {
                const int drow = tw * 32 + dt * 16 + l15;
                half8 bvr = ldh64(Vt[0], drow, kc * 32 + quad * 8);
                half8 bvi = ldh64(Vt[1], drow, kc * 32 + quad * 8);
                #pragma unroll
                for (int qt = 0; qt < 2; ++qt) {
                    MFMA16(acc[qt][dt][0], ap[qt][0], bvr);
                    MFMA16(acc[qt][dt][1], ap[qt][0], bvi);
                    MFMA16(acc[qt][dt][2], ap[qt][1], bvr);
                    MFMA16(acc[qt][dt][3], ap[qt][1], bvi);
                }
            }
        }

        // ---- SYNC2: K-waves land K(t+1) (published to all by the barrier);
        //      everyone done with Vt/Ps/old K buf. ----
        if (isK) asm volatile("s_waitcnt vmcnt(0)" ::: "memory");
        __builtin_amdgcn_s_barrier();
        asm volatile("" ::: "memory");

        // swap K buffers (register moves)
        const unsigned short* tr;
        tr = Kr_c; Kr_c = Kr_n; Kr_n = tr;
        tr = Ki_c; Ki_c = Ki_n; Ki_n = tr;
        unsigned short* ts = kst_nxt; kst_nxt = kst_alt; kst_alt = ts;
    }
#undef GLD

    // ---- combine l: quad-reduce (lane's k-subset -> full k-half), store ----
    #pragma unroll
    for (int qt = 0; qt < 2; ++qt)
        #pragma unroll
        for (int p = 0; p < 2; ++p) {
            float v = lacc[qt][p];
            v += __shfl_xor(v, 16);
            v += __shfl_xor(v, 32);
            if (lane < 16) lbuf[p][tw][sw * 32 + qt * 16 + lane] = v;
        }
    __syncthreads();

    // ---- epilogue: normalize, combine complex, store fp16 planes ----
    #pragma unroll
    for (int qt = 0; qt < 2; ++qt)
        #pragma unroll
        for (int reg = 0; reg < 4; ++reg) {
            const int qloc = sw * 32 + qt * 16 + quad * 4 + reg;
            const float ir = 1.f / (lbuf[0][0][qloc] + lbuf[0][1][qloc]);
            const float ii = 1.f / (lbuf[1][0][qloc] + lbuf[1][1][qloc]);
            #pragma unroll
            for (int dt = 0; dt < 2; ++dt) {
                const int d = tw * 32 + dt * 16 + l15;
                union { _Float16 h; unsigned short u; } cr, ci;
                cr.h = (_Float16)(acc[qt][dt][0][reg] * ir - acc[qt][dt][3][reg] * ii);
                ci.h = (_Float16)(acc[qt][dt][1][reg] * ir + acc[qt][dt][2][reg] * ii);
                size_t o = ((size_t)b * SS + q0 + qloc) * DD + h * DHD + d;
                ObR[o] = cr.u;
                ObI[o] = ci.u;
            }
        }
}

// ---------------------------------------------------------------------------
// Kernel 3: residual + dual LayerNorm over D (biased var, eps inside sqrt)
// ---------------------------------------------------------------------------
__global__ __launch_bounds__(256)
void ln_kernel(const unsigned short* __restrict__ OrP, const unsigned short* __restrict__ OiP,
               const float2* __restrict__ Qin,
               const float* __restrict__ gr, const float* __restrict__ br,
               const float* __restrict__ gi, const float* __restrict__ bi,
               float2* __restrict__ out) {
    const int row = blockIdx.x;           // b*S + s
    const int tid = threadIdx.x;
    const size_t base = (size_t)row * DD;
    const int e0 = 2 * tid, e1 = 2 * tid + 1;

    union { unsigned int u; _Float16 h[2]; } tr, ti;
    tr.u = *(const unsigned int*)(OrP + base + e0);
    ti.u = *(const unsigned int*)(OiP + base + e0);
    float2 r0 = Qin[base + e0];
    float2 r1 = Qin[base + e1];
    float xr0 = (float)tr.h[0] + r0.x;
    float xr1 = (float)tr.h[1] + r1.x;
    float xi0 = (float)ti.h[0] + r0.y;
    float xi1 = (float)ti.h[1] + r1.y;

    float sr = xr0 + xr1;
    float si = xi0 + xi1;
    float qr = xr0 * xr0 + xr1 * xr1;
    float qi = xi0 * xi0 + xi1 * xi1;
    #pragma unroll
    for (int off = 32; off > 0; off >>= 1) {
        sr += __shfl_down(sr, off);
        si += __shfl_down(si, off);
        qr += __shfl_down(qr, off);
        qi += __shfl_down(qi, off);
    }
    __shared__ float red[4][4];
    __shared__ float stat[4];
    int lane = tid & 63, wid = tid >> 6;
    if (lane == 0) { red[wid][0] = sr; red[wid][1] = si; red[wid][2] = qr; red[wid][3] = qi; }
    __syncthreads();
    if (tid == 0) {
        sr = red[0][0] + red[1][0] + red[2][0] + red[3][0];
        si = red[0][1] + red[1][1] + red[2][1] + red[3][1];
        qr = red[0][2] + red[1][2] + red[2][2] + red[3][2];
        qi = red[0][3] + red[1][3] + red[2][3] + red[3][3];
        float mur = sr * (1.f / DD), mui = si * (1.f / DD);
        float vr = qr * (1.f / DD) - mur * mur;
        float vi = qi * (1.f / DD) - mui * mui;
        stat[0] = mur; stat[1] = mui;
        stat[2] = rsqrtf(vr + LN_EPS); stat[3] = rsqrtf(vi + LN_EPS);
    }
    __syncthreads();
    float mur = stat[0], mui = stat[1], rsr = stat[2], rsi = stat[3];
    out[base + e0] = make_float2((xr0 - mur) * rsr * gr[e0] + br[e0],
                                 (xi0 - mui) * rsi * gi[e0] + bi[e0]);
    out[base + e1] = make_float2((xr1 - mur) * rsr * gr[e1] + br[e1],
                                 (xi1 - mui) * rsi * gi[e1] + bi[e1]);
}

// ---------------------------------------------------------------------------
extern "C" void kernel_launch(void* const* d_in, const int* in_sizes, int n_in,
                              void* d_out, int out_size, void* d_ws, size_t ws_size,
                              hipStream_t stream) {
    const float2* q  = (const float2*)d_in[0];
    const float2* k  = (const float2*)d_in[1];
    const float2* v  = (const float2*)d_in[2];
    const float2* Wq = (const float2*)d_in[3];
    const float2* bq = (const float2*)d_in[4];
    const float2* Wk = (const float2*)d_in[5];
    const float2* bk = (const float2*)d_in[6];
    const float2* Wv = (const float2*)d_in[7];
    const float2* bv = (const float2*)d_in[8];
    const float*  gr = (const float*)d_in[9];
    const float*  br = (const float*)d_in[10];
    const float*  gi = (const float*)d_in[11];
    const float*  bi = (const float*)d_in[12];

    // workspace (fp16 elements): X planes, W planes, Q/K/V planes, Ob planes
    unsigned short* XP  = (unsigned short*)d_ws;           // 3*2*PL (blocked)
    unsigned short* WP  = XP + (size_t)6 * PL;             // 3*2*WPL (blocked)
    unsigned short* QG  = WP + (size_t)6 * WPL;            // 2*PL  [BH][S][64]
    unsigned short* KG  = QG + (size_t)2 * PL;             // 2*PL  [BH][S][64]
    unsigned short* VG  = KG + (size_t)2 * PL;             // 2*PL  [BH][64][S] (transposed)
    unsigned short* ObR = VG + (size_t)2 * PL;             // PL
    unsigned short* ObI = ObR + (size_t)PL;                // PL

    cvt_kernel<<<dim3(4096, 3), 256, 0, stream>>>(q, k, v, XP, PL);
    cvt_kernel<<<dim3(512, 3), 256, 0, stream>>>(Wq, Wk, Wv, WP, WPL);
    proj_kernel<<<dim3(32, 4, 3), 512, 0, stream>>>(XP, WP, bq, bk, bv, QG, KG, VG);
    attn_kernel<<<dim3(512), 256, 0, stream>>>(QG, KG, VG, ObR, ObI);
    ln_kernel<<<dim3(BB * SS), 256, 0, stream>>>(ObR, ObI, q, gr, br, gi, bi, (float2*)d_out);
}

// Round 7
// 209.299 us; speedup vs baseline: 1.0168x; 1.0168x over previous
//
#include <hip/hip_runtime.h>
#include <math.h>

#define BB  4
#define SS  1024
#define DD  512
#define HH  8
#define DHD 64
#define PL  2097152      // elements per Q/K/V/Ob plane (also B*S*D)
#define WPL 262144       // elements per W plane

constexpr float LN_EPS = 1e-5f;

using half4 = __attribute__((ext_vector_type(4))) _Float16;
using half8 = __attribute__((ext_vector_type(8))) _Float16;
using f32x4 = __attribute__((ext_vector_type(4))) float;

__device__ __forceinline__ half8 negh(half8 a) {
    union { half8 h; unsigned int u[4]; } t;
    t.h = a;
    #pragma unroll
    for (int i = 0; i < 4; ++i) t.u[i] ^= 0x80008000u;
    return t.h;
}
// 64-wide swizzled rows (XOR (row&7)<<3, 8-half granules): conflict-free b128
__device__ __forceinline__ half8 ldh64(const unsigned short* p, int row, int col) {
    return *(const half8*)(p + row * 64 + (col ^ ((row & 7) << 3)));
}
// logical [128 rows][32 halfs] stored as phys [64][64] with granule involution:
// logical (r,g2) lives at phys row R=r>>1, slot G^(R&7), G=((r&1)<<2)|g2.
__device__ __forceinline__ half8 ldh32(const unsigned short* p, int r, int g2) {
    const int R = r >> 1;
    const int G = ((r & 1) << 2) | g2;
    return *(const half8*)(p + R * 64 + ((G ^ (R & 7)) << 3));
}
// packed f32x2 -> f16x2 (RTZ), as raw u32
__device__ __forceinline__ unsigned int cvtpk(float a, float b) {
    union { decltype(__builtin_amdgcn_cvt_pkrtz(0.f, 0.f)) v; unsigned int u; } t;
    t.v = __builtin_amdgcn_cvt_pkrtz(a, b);
    return t.u;
}
// native v_exp_f32 (2^x) — NOT the precise OCML exp2f path
__device__ __forceinline__ float ex2(float x) { return __builtin_amdgcn_exp2f(x); }
#define MFMA16(acc, a, b) acc = __builtin_amdgcn_mfma_f32_16x16x32_f16(a, b, acc, 0, 0, 0)

// ---------------------------------------------------------------------------
// Kernel 0: fp32 complex -> fp16 r/i planes, TILE-BLOCKED layout:
// plane stored as [m/128][d/64][128][64] so proj's K-step strips are
// contiguous (HBM-stream friendly) instead of 128B-at-1KB-stride.
// ---------------------------------------------------------------------------
__global__ __launch_bounds__(256)
void cvt_kernel(const float2* __restrict__ s0, const float2* __restrict__ s1,
                const float2* __restrict__ s2, unsigned short* __restrict__ dst,
                int planeElems) {
    const int z = blockIdx.y;
    const float2* src = z == 0 ? s0 : (z == 1 ? s1 : s2);
    unsigned short* base = dst + (size_t)z * 2 * planeElems;
    const int idx = (blockIdx.x * 256 + threadIdx.x) * 2;   // complex index (even)
    float4 t = *(const float4*)(src + idx);
    const int m = idx >> 9;          // row
    const int d = idx & 511;         // col (even)
    const int ob = (((m >> 7) << 3) + (d >> 6)) * 8192 + ((m & 127) << 6) + (d & 63);
    union { _Float16 h[2]; unsigned int u; } r, i;
    r.h[0] = (_Float16)t.x; r.h[1] = (_Float16)t.z;
    i.h[0] = (_Float16)t.y; i.h[1] = (_Float16)t.w;
    *(unsigned int*)(base + ob) = r.u;
    *(unsigned int*)(base + planeElems + ob) = i.u;
}

// ---------------------------------------------------------------------------
// Kernel 1: complex projection — round-7: back to 4-wave 64x64 wave-tiles
// (round-6's 8-wave 64x32 halved per-wave MFMA while raising fragment
// re-reads -> regression), PLUS BK=32 cross-step double-buffering with
// counted waits (the attn-proven T3/T4 pattern):
//   step s: issue stage(s+1) -> alt buffer (8 DMAs/wave), compute step s
//   (16 ds_read_b128 + 64 MFMA = the hiding window), vmcnt(0) + s_barrier.
// One barrier/step; 2 x 32KB buffers = 64KB -> still 2 blocks/CU.
// Staging swizzle folded into per-lane global source (G=(lane&7)^(lane>>3)),
// linear LDS dest, ldh32 applies the same involution on read.
// ---------------------------------------------------------------------------
__global__ __launch_bounds__(256, 2)
void proj_kernel(const unsigned short* __restrict__ XP,
                 const unsigned short* __restrict__ WP,
                 const float2* __restrict__ bq, const float2* __restrict__ bk,
                 const float2* __restrict__ bv,
                 unsigned short* __restrict__ QG, unsigned short* __restrict__ KG,
                 unsigned short* __restrict__ VG) {
    const unsigned short* XR = XP + (size_t)blockIdx.z * 2 * PL;
    const unsigned short* XI = XR + PL;
    const unsigned short* WRp = WP + (size_t)blockIdx.z * 2 * WPL;
    const unsigned short* WIp = WRp + WPL;
    const float2* bias; unsigned short* outP;
    if (blockIdx.z == 0)      { bias = bq; outP = QG; }
    else if (blockIdx.z == 1) { bias = bk; outP = KG; }
    else                      { bias = bv; outP = VG; }
    const bool isV = (blockIdx.z == 2);

    // [buf][plane][phys 64x64] = 8KB each; X 32KB + W 32KB = 64KB total
    __shared__ __align__(16) unsigned short Xs[2][2][64 * 64];
    __shared__ __align__(16) unsigned short Ws[2][2][64 * 64];

    const int tid  = threadIdx.x;
    const int w    = tid >> 6;
    const int lane = tid & 63;
    const int quad = lane >> 4;
    const int l15  = lane & 15;
    const int wm   = w >> 1;                 // m half of the 128x128 tile
    const int we   = w & 1;                  // e half
    const int m0   = blockIdx.x * 128;
    const int e0   = blockIdx.y * 128;

    // ---- staging lane geometry (involution folded into global source) ----
    const int srow8 = lane >> 3;             // 0..7
    const int G     = (lane & 7) ^ srow8;    // slot involution
    const int rl    = srow8 * 2 + (G >> 2);  // logical row within 16-row group
    const int g2s   = G & 3;                 // k-granule (8 halfs)

    const unsigned short* gplane;
    unsigned short *lb0, *lb1;
    int row0;
    if (w == 0)      { gplane = XR;  row0 = m0; lb0 = &Xs[0][0][0]; lb1 = &Xs[1][0][0]; }
    else if (w == 1) { gplane = XI;  row0 = m0; lb0 = &Xs[0][1][0]; lb1 = &Xs[1][1][0]; }
    else if (w == 2) { gplane = WRp; row0 = e0; lb0 = &Ws[0][0][0]; lb1 = &Ws[1][0][0]; }
    else             { gplane = WIp; row0 = e0; lb0 = &Ws[0][1][0]; lb1 = &Ws[1][1][0]; }
    // blocked layout: (row, d = s*32 + g2*8 + e) at (s>>1)*8192 + row*64 + (s&1)*32 + g2*8
    const unsigned short* gsrc = gplane + (size_t)row0 * DD + rl * 64 + g2s * 8;

#define PSTAGE(S, LB) { \
        const unsigned short* _g = gsrc + ((S) >> 1) * 8192 + ((S) & 1) * 32; \
        _Pragma("unroll") \
        for (int j = 0; j < 8; ++j) \
            __builtin_amdgcn_global_load_lds( \
                (const __attribute__((address_space(1))) void*)(_g + j * 1024), \
                (__attribute__((address_space(3))) void*)((LB) + j * 512), \
                16, 0, 0); }

    f32x4 Sr[4][4], Si[4][4];                // [mf][ef]
    #pragma unroll
    for (int a = 0; a < 4; ++a)
        #pragma unroll
        for (int c = 0; c < 4; ++c) { Sr[a][c] = (f32x4)0.f; Si[a][c] = (f32x4)0.f; }

    PSTAGE(0, lb0);
    __syncthreads();                         // buf0 ready (full drain once)

    for (int s = 0; s < 16; ++s) {
        const int bs = s & 1;
        if (s < 15) PSTAGE(s + 1, bs ? lb0 : lb1);   // prefetch next K-slice

        const unsigned short* xb0 = &Xs[bs][0][0];
        const unsigned short* xb1 = &Xs[bs][1][0];
        const unsigned short* wb0 = &Ws[bs][0][0];
        const unsigned short* wb1 = &Ws[bs][1][0];

        half8 xr[4], xi[4];
        #pragma unroll
        for (int mf = 0; mf < 4; ++mf) {
            const int mr = wm * 64 + mf * 16 + l15;
            xr[mf] = ldh32(xb0, mr, quad);
            xi[mf] = ldh32(xb1, mr, quad);
        }
        #pragma unroll
        for (int ef = 0; ef < 4; ++ef) {
            const int er = we * 64 + ef * 16 + l15;
            half8 wr  = ldh32(wb0, er, quad);
            half8 wi  = ldh32(wb1, er, quad);
            half8 wmi = negh(wi);
            #pragma unroll
            for (int mf = 0; mf < 4; ++mf) {
                MFMA16(Sr[mf][ef], xr[mf], wr);    // Xr.Wr
                MFMA16(Sr[mf][ef], xi[mf], wmi);   // -Xi.Wi
                MFMA16(Si[mf][ef], xr[mf], wi);    // Xr.Wi
                MFMA16(Si[mf][ef], xi[mf], wr);    // Xi.Wr
            }
        }
        // drain own prefetch (hidden under the 16 ds_reads + 64 MFMA above),
        // then publish: one barrier per step.
        asm volatile("s_waitcnt vmcnt(0)" ::: "memory");
        __builtin_amdgcn_s_barrier();
        asm volatile("" ::: "memory");
    }
#undef PSTAGE

    // ---- epilogue: + bias, fp16, write planes (V transposed) ----
    #pragma unroll
    for (int ef = 0; ef < 4; ++ef) {
        const int eg  = e0 + we * 64 + ef * 16 + l15;   // global out column
        const int hh  = eg >> 6;                         // head
        const int col = eg & 63;
        float2 bb = bias[eg];
        #pragma unroll
        for (int mf = 0; mf < 4; ++mf) {
            #pragma unroll
            for (int reg = 0; reg < 4; ++reg) {
                int m = m0 + wm * 64 + mf * 16 + quad * 4 + reg;
                int bidx = m >> 10;
                int sidx = m & 1023;
                int bh = bidx * HH + hh;
                union { _Float16 h; unsigned short u; } cr, ci;
                cr.h = (_Float16)(Sr[mf][ef][reg] + bb.x);
                ci.h = (_Float16)(Si[mf][ef][reg] + bb.y);
                size_t o = isV ? ((size_t)bh * DHD + col) * SS + sidx
                               : ((size_t)bh * SS + sidx) * DHD + col;
                outP[0 * PL + o] = cr.u;
                outP[1 * PL + o] = ci.u;
            }
        }
    }
}

// ---------------------------------------------------------------------------
// Kernel 2: fp16 MFMA flash attention, S^T formulation. (unchanged round-6)
// Counted-vmcnt sync (T4). Raw s_barrier + role-targeted waits:
//   SYNC1: all waves lgkmcnt(0) (publish Ps); V-waves vmcnt(0) (V(t) landed).
//          K-waves keep their 8 K(t+1) DMAs in flight across the barrier.
//   SYNC2: K-waves vmcnt(0) (K(t+1) landed for next iter's scores).
// ---------------------------------------------------------------------------
#define AWID 72
__global__ __launch_bounds__(256, 2)
void attn_kernel(const unsigned short* __restrict__ QG, const unsigned short* __restrict__ KG,
                 const unsigned short* __restrict__ VG,
                 unsigned short* __restrict__ ObR, unsigned short* __restrict__ ObI) {
    __shared__ __align__(16) unsigned short Ks[2][2][64 * 64]; // [buf][r,i][k][d] swizzled
    __shared__ __align__(16) unsigned short Vt[2][64 * 64];    // [r,i][d][k] swizzled
    __shared__ __align__(16) unsigned short Ps[2][64 * AWID];  // [r,i][q][k]
    __shared__ float lbuf[2][2][64];                           // [plane][k-half][q]

    const int n   = blockIdx.x;
    const int bh  = (n & 7) * 4 + (n >> 7);       // XCD-local bh group
    const int q0  = ((n >> 3) & 15) * 64;
    const int b   = bh >> 3;
    const int h   = bh & 7;

    const int tid  = threadIdx.x;
    const int w    = tid >> 6;
    const int lane = tid & 63;
    const int quad = lane >> 4;
    const int l15  = lane & 15;
    const int sw   = w & 1;        // q-half (both phases)
    const int tw   = w >> 1;       // k-half (scores) / d-half (PV)

    // ---- DMA staging setup: waves 0,1 own K planes; waves 2,3 own V planes ----
    const int srow = lane >> 3;    // 0..7 (row within 8-row DMA group)
    const int sg   = lane & 7;     // dest granule; source granule = sg^srow
    const bool isK = (w < 2);
    const unsigned short* bpK = nullptr;
    const unsigned short* bpV = nullptr;
    unsigned short* ldV = nullptr;
    if (isK) {
        bpK = KG + (size_t)w * PL + (size_t)bh * SS * DHD + srow * DHD + ((sg ^ srow) << 3);
    } else {
        bpV = VG + (size_t)(w - 2) * PL + (size_t)bh * DHD * SS + srow * SS + ((sg ^ srow) << 3);
        ldV = &Vt[w - 2][0];
    }

#define GLD(SRC, DST) __builtin_amdgcn_global_load_lds( \
        (const __attribute__((address_space(1))) void*)(SRC), \
        (__attribute__((address_space(3))) void*)(DST), 16, 0, 0)

    // ---- prologue: stage K(0) into buf0 ----
    if (isK) {
        unsigned short* ld = &Ks[0][w][0];
        #pragma unroll
        for (int j = 0; j < 8; ++j) GLD(bpK + j * 8 * DHD, ld + j * 512);
    }

    // Q in B-layout registers: lane = q col, quad*8+j = d within 32-window
    half8 qfr[2][2], qfi[2][2], qfmi[2][2];       // [qt][kc]
    #pragma unroll
    for (int qt = 0; qt < 2; ++qt)
        #pragma unroll
        for (int kc = 0; kc < 2; ++kc) {
            size_t qa = ((size_t)bh * SS + q0 + sw * 32 + qt * 16 + l15) * DHD + kc * 32 + quad * 8;
            qfr[qt][kc]  = *(const half8*)(QG + qa);
            qfi[qt][kc]  = *(const half8*)(QG + PL + qa);
            qfmi[qt][kc] = negh(qfi[qt][kc]);
        }

    f32x4 acc[2][2][4];            // [qt][dt][PrVr,PrVi,PiVr,PiVi]
    #pragma unroll
    for (int qt = 0; qt < 2; ++qt)
        #pragma unroll
        for (int dt = 0; dt < 2; ++dt)
            #pragma unroll
            for (int p = 0; p < 4; ++p) acc[qt][dt][p] = (f32x4)0.f;
    float lacc[2][2] = {{0.f, 0.f}, {0.f, 0.f}};  // [qt][plane]

    constexpr float EC = 0.18033688011112042f;    // log2(e)/8

    __syncthreads();               // K(0) staged (full drain once, prologue)

    // double-buffer pointer sets (swapped per iteration; register moves only)
    const unsigned short* Kr_c = &Ks[0][0][0];
    const unsigned short* Ki_c = &Ks[0][1][0];
    const unsigned short* Kr_n = &Ks[1][0][0];
    const unsigned short* Ki_n = &Ks[1][1][0];
    unsigned short* kst_nxt = isK ? &Ks[1][w][0] : nullptr;
    unsigned short* kst_alt = isK ? &Ks[0][w][0] : nullptr;

    for (int t = 0; t < 16; ++t) {
        // ---- issue prefetch: K(t+1) -> next buf (waves 0,1); V(t) (waves 2,3)
        if (isK) {
            if (t < 15) {
                const unsigned short* g = bpK + (size_t)(t + 1) * 64 * DHD;
                #pragma unroll
                for (int j = 0; j < 8; ++j) GLD(g + j * 8 * DHD, kst_nxt + j * 512);
            }
        } else {
            const unsigned short* g = bpV + (size_t)t * 64;
            #pragma unroll
            for (int j = 0; j < 8; ++j) GLD(g + j * 8 * SS, ldV + j * 512);
        }

        // ---- scores: S^T[k32][q32] from current K buffer ----
        f32x4 Sr[2][2], Si[2][2];   // [kt2][qt]
        #pragma unroll
        for (int a = 0; a < 2; ++a)
            #pragma unroll
            for (int c = 0; c < 2; ++c) { Sr[a][c] = (f32x4)0.f; Si[a][c] = (f32x4)0.f; }
        #pragma unroll
        for (int kc = 0; kc < 2; ++kc) {
            const int dl = kc * 32 + quad * 8;
            #pragma unroll
            for (int kt2 = 0; kt2 < 2; ++kt2) {
                const int krow = tw * 32 + kt2 * 16 + l15;
                half8 akr = ldh64(Kr_c, krow, dl);
                half8 aki = ldh64(Ki_c, krow, dl);
                #pragma unroll
                for (int qt = 0; qt < 2; ++qt) {
                    MFMA16(Sr[kt2][qt], akr, qfr[qt][kc]);    // K_r . Q_r
                    MFMA16(Sr[kt2][qt], aki, qfmi[qt][kc]);   // -K_i . Q_i
                    MFMA16(Si[kt2][qt], aki, qfr[qt][kc]);    // K_i . Q_r
                    MFMA16(Si[kt2][qt], akr, qfi[qt][kc]);    // K_r . Q_i
                }
            }
        }

        // ---- exp -> P (packed b64, q-major), l partial per lane ----
        #pragma unroll
        for (int kt2 = 0; kt2 < 2; ++kt2)
            #pragma unroll
            for (int qt = 0; qt < 2; ++qt) {
                float er0 = ex2(Sr[kt2][qt][0] * EC), er1 = ex2(Sr[kt2][qt][1] * EC);
                float er2 = ex2(Sr[kt2][qt][2] * EC), er3 = ex2(Sr[kt2][qt][3] * EC);
                float ei0 = ex2(Si[kt2][qt][0] * EC), ei1 = ex2(Si[kt2][qt][1] * EC);
                float ei2 = ex2(Si[kt2][qt][2] * EC), ei3 = ex2(Si[kt2][qt][3] * EC);
                lacc[qt][0] += (er0 + er1) + (er2 + er3);
                lacc[qt][1] += (ei0 + ei1) + (ei2 + ei3);
                const int qrow = sw * 32 + qt * 16 + l15;
                const int kcol = tw * 32 + kt2 * 16 + quad * 4;
                uint2 pr, pi;
                pr.x = cvtpk(er0, er1); pr.y = cvtpk(er2, er3);
                pi.x = cvtpk(ei0, ei1); pi.y = cvtpk(ei2, ei3);
                *(uint2*)&Ps[0][qrow * AWID + kcol] = pr;
                *(uint2*)&Ps[1][qrow * AWID + kcol] = pi;
            }

        // ---- SYNC1: publish Ps (lgkm); V-waves land V(t); K prefetch stays
        //      in flight across the barrier (counted-vmcnt, T4). ----
        asm volatile("s_waitcnt lgkmcnt(0)" ::: "memory");
        if (!isK) asm volatile("s_waitcnt vmcnt(0)" ::: "memory");
        __builtin_amdgcn_s_barrier();
        asm volatile("" ::: "memory");

        // ---- PV: out tile q32 (sw) x d32 (tw), k64 accumulation ----
        #pragma unroll
        for (int kc = 0; kc < 2; ++kc) {
            half8 ap[2][2];   // [qt][plane]
            #pragma unroll
            for (int qt = 0; qt < 2; ++qt) {
                const int qrow = sw * 32 + qt * 16 + l15;
                ap[qt][0] = *(const half8*)&Ps[0][qrow * AWID + kc * 32 + quad * 8];
                ap[qt][1] = *(const half8*)&Ps[1][qrow * AWID + kc * 32 + quad * 8];
            }
            #pragma unroll
            for (int dt = 0; dt < 2; ++dt) {
                const int drow = tw * 32 + dt * 16 + l15;
                half8 bvr = ldh64(Vt[0], drow, kc * 32 + quad * 8);
                half8 bvi = ldh64(Vt[1], drow, kc * 32 + quad * 8);
                #pragma unroll
                for (int qt = 0; qt < 2; ++qt) {
                    MFMA16(acc[qt][dt][0], ap[qt][0], bvr);
                    MFMA16(acc[qt][dt][1], ap[qt][0], bvi);
                    MFMA16(acc[qt][dt][2], ap[qt][1], bvr);
                    MFMA16(acc[qt][dt][3], ap[qt][1], bvi);
                }
            }
        }

        // ---- SYNC2: K-waves land K(t+1) (published to all by the barrier);
        //      everyone done with Vt/Ps/old K buf. ----
        if (isK) asm volatile("s_waitcnt vmcnt(0)" ::: "memory");
        __builtin_amdgcn_s_barrier();
        asm volatile("" ::: "memory");

        // swap K buffers (register moves)
        const unsigned short* tr;
        tr = Kr_c; Kr_c = Kr_n; Kr_n = tr;
        tr = Ki_c; Ki_c = Ki_n; Ki_n = tr;
        unsigned short* ts = kst_nxt; kst_nxt = kst_alt; kst_alt = ts;
    }
#undef GLD

    // ---- combine l: quad-reduce (lane's k-subset -> full k-half), store ----
    #pragma unroll
    for (int qt = 0; qt < 2; ++qt)
        #pragma unroll
        for (int p = 0; p < 2; ++p) {
            float v = lacc[qt][p];
            v += __shfl_xor(v, 16);
            v += __shfl_xor(v, 32);
            if (lane < 16) lbuf[p][tw][sw * 32 + qt * 16 + lane] = v;
        }
    __syncthreads();

    // ---- epilogue: normalize, combine complex, store fp16 planes ----
    #pragma unroll
    for (int qt = 0; qt < 2; ++qt)
        #pragma unroll
        for (int reg = 0; reg < 4; ++reg) {
            const int qloc = sw * 32 + qt * 16 + quad * 4 + reg;
            const float ir = 1.f / (lbuf[0][0][qloc] + lbuf[0][1][qloc]);
            const float ii = 1.f / (lbuf[1][0][qloc] + lbuf[1][1][qloc]);
            #pragma unroll
            for (int dt = 0; dt < 2; ++dt) {
                const int d = tw * 32 + dt * 16 + l15;
                union { _Float16 h; unsigned short u; } cr, ci;
                cr.h = (_Float16)(acc[qt][dt][0][reg] * ir - acc[qt][dt][3][reg] * ii);
                ci.h = (_Float16)(acc[qt][dt][1][reg] * ir + acc[qt][dt][2][reg] * ii);
                size_t o = ((size_t)b * SS + q0 + qloc) * DD + h * DHD + d;
                ObR[o] = cr.u;
                ObI[o] = ci.u;
            }
        }
}

// ---------------------------------------------------------------------------
// Kernel 3: residual + dual LayerNorm over D (biased var, eps inside sqrt)
// ---------------------------------------------------------------------------
__global__ __launch_bounds__(256)
void ln_kernel(const unsigned short* __restrict__ OrP, const unsigned short* __restrict__ OiP,
               const float2* __restrict__ Qin,
               const float* __restrict__ gr, const float* __restrict__ br,
               const float* __restrict__ gi, const float* __restrict__ bi,
               float2* __restrict__ out) {
    const int row = blockIdx.x;           // b*S + s
    const int tid = threadIdx.x;
    const size_t base = (size_t)row * DD;
    const int e0 = 2 * tid, e1 = 2 * tid + 1;

    union { unsigned int u; _Float16 h[2]; } tr, ti;
    tr.u = *(const unsigned int*)(OrP + base + e0);
    ti.u = *(const unsigned int*)(OiP + base + e0);
    float2 r0 = Qin[base + e0];
    float2 r1 = Qin[base + e1];
    float xr0 = (float)tr.h[0] + r0.x;
    float xr1 = (float)tr.h[1] + r1.x;
    float xi0 = (float)ti.h[0] + r0.y;
    float xi1 = (float)ti.h[1] + r1.y;

    float sr = xr0 + xr1;
    float si = xi0 + xi1;
    float qr = xr0 * xr0 + xr1 * xr1;
    float qi = xi0 * xi0 + xi1 * xi1;
    #pragma unroll
    for (int off = 32; off > 0; off >>= 1) {
        sr += __shfl_down(sr, off);
        si += __shfl_down(si, off);
        qr += __shfl_down(qr, off);
        qi += __shfl_down(qi, off);
    }
    __shared__ float red[4][4];
    __shared__ float stat[4];
    int lane = tid & 63, wid = tid >> 6;
    if (lane == 0) { red[wid][0] = sr; red[wid][1] = si; red[wid][2] = qr; red[wid][3] = qi; }
    __syncthreads();
    if (tid == 0) {
        sr = red[0][0] + red[1][0] + red[2][0] + red[3][0];
        si = red[0][1] + red[1][1] + red[2][1] + red[3][1];
        qr = red[0][2] + red[1][2] + red[2][2] + red[3][2];
        qi = red[0][3] + red[1][3] + red[2][3] + red[3][3];
        float mur = sr * (1.f / DD), mui = si * (1.f / DD);
        float vr = qr * (1.f / DD) - mur * mur;
        float vi = qi * (1.f / DD) - mui * mui;
        stat[0] = mur; stat[1] = mui;
        stat[2] = rsqrtf(vr + LN_EPS); stat[3] = rsqrtf(vi + LN_EPS);
    }
    __syncthreads();
    float mur = stat[0], mui = stat[1], rsr = stat[2], rsi = stat[3];
    out[base + e0] = make_float2((xr0 - mur) * rsr * gr[e0] + br[e0],
                                 (xi0 - mui) * rsi * gi[e0] + bi[e0]);
    out[base + e1] = make_float2((xr1 - mur) * rsr * gr[e1] + br[e1],
                                 (xi1 - mui) * rsi * gi[e1] + bi[e1]);
}

// ---------------------------------------------------------------------------
extern "C" void kernel_launch(void* const* d_in, const int* in_sizes, int n_in,
                              void* d_out, int out_size, void* d_ws, size_t ws_size,
                              hipStream_t stream) {
    const float2* q  = (const float2*)d_in[0];
    const float2* k  = (const float2*)d_in[1];
    const float2* v  = (const float2*)d_in[2];
    const float2* Wq = (const float2*)d_in[3];
    const float2* bq = (const float2*)d_in[4];
    const float2* Wk = (const float2*)d_in[5];
    const float2* bk = (const float2*)d_in[6];
    const float2* Wv = (const float2*)d_in[7];
    const float2* bv = (const float2*)d_in[8];
    const float*  gr = (const float*)d_in[9];
    const float*  br = (const float*)d_in[10];
    const float*  gi = (const float*)d_in[11];
    const float*  bi = (const float*)d_in[12];

    // workspace (fp16 elements): X planes, W planes, Q/K/V planes, Ob planes
    unsigned short* XP  = (unsigned short*)d_ws;           // 3*2*PL (blocked)
    unsigned short* WP  = XP + (size_t)6 * PL;             // 3*2*WPL (blocked)
    unsigned short* QG  = WP + (size_t)6 * WPL;            // 2*PL  [BH][S][64]
    unsigned short* KG  = QG + (size_t)2 * PL;             // 2*PL  [BH][S][64]
    unsigned short* VG  = KG + (size_t)2 * PL;             // 2*PL  [BH][64][S] (transposed)
    unsigned short* ObR = VG + (size_t)2 * PL;             // PL
    unsigned short* ObI = ObR + (size_t)PL;                // PL

    cvt_kernel<<<dim3(4096, 3), 256, 0, stream>>>(q, k, v, XP, PL);
    cvt_kernel<<<dim3(512, 3), 256, 0, stream>>>(Wq, Wk, Wv, WP, WPL);
    proj_kernel<<<dim3(32, 4, 3), 256, 0, stream>>>(XP, WP, bq, bk, bv, QG, KG, VG);
    attn_kernel<<<dim3(512), 256, 0, stream>>>(QG, KG, VG, ObR, ObI);
    ln_kernel<<<dim3(BB * SS), 256, 0, stream>>>(ObR, ObI, q, gr, br, gi, bi, (float2*)d_out);
}

// Round 8
// 205.919 us; speedup vs baseline: 1.0335x; 1.0164x over previous
//
#include <hip/hip_runtime.h>
#include <math.h>

#define BB  4
#define SS  1024
#define DD  512
#define HH  8
#define DHD 64
#define PL  2097152      // elements per Q/K/V/Ob plane (also B*S*D)
#define WPL 262144       // elements per W plane

constexpr float LN_EPS = 1e-5f;

using half4 = __attribute__((ext_vector_type(4))) _Float16;
using half8 = __attribute__((ext_vector_type(8))) _Float16;
using f32x4 = __attribute__((ext_vector_type(4))) float;

__device__ __forceinline__ half8 negh(half8 a) {
    union { half8 h; unsigned int u[4]; } t;
    t.h = a;
    #pragma unroll
    for (int i = 0; i < 4; ++i) t.u[i] ^= 0x80008000u;
    return t.h;
}
// 64-wide swizzled rows (XOR (row&7)<<3, 8-half granules): conflict-free b128
__device__ __forceinline__ half8 ldh64(const unsigned short* p, int row, int col) {
    return *(const half8*)(p + row * 64 + (col ^ ((row & 7) << 3)));
}
// packed f32x2 -> f16x2 (RTZ), as raw u32
__device__ __forceinline__ unsigned int cvtpk(float a, float b) {
    union { decltype(__builtin_amdgcn_cvt_pkrtz(0.f, 0.f)) v; unsigned int u; } t;
    t.v = __builtin_amdgcn_cvt_pkrtz(a, b);
    return t.u;
}
// native v_exp_f32 (2^x) — NOT the precise OCML exp2f path
__device__ __forceinline__ float ex2(float x) { return __builtin_amdgcn_exp2f(x); }
#define MFMA16(acc, a, b) acc = __builtin_amdgcn_mfma_f32_16x16x32_f16(a, b, acc, 0, 0, 0)

// ---------------------------------------------------------------------------
// Kernel 0: fp32 complex -> fp16 r/i planes, TILE-BLOCKED layout:
// plane stored as [m/128][d/64][128][64] so proj's K-step strips are
// contiguous (HBM-stream friendly) instead of 128B-at-1KB-stride.
// ---------------------------------------------------------------------------
__global__ __launch_bounds__(256)
void cvt_kernel(const float2* __restrict__ s0, const float2* __restrict__ s1,
                const float2* __restrict__ s2, unsigned short* __restrict__ dst,
                int planeElems) {
    const int z = blockIdx.y;
    const float2* src = z == 0 ? s0 : (z == 1 ? s1 : s2);
    unsigned short* base = dst + (size_t)z * 2 * planeElems;
    const int idx = (blockIdx.x * 256 + threadIdx.x) * 2;   // complex index (even)
    float4 t = *(const float4*)(src + idx);
    const int m = idx >> 9;          // row
    const int d = idx & 511;         // col (even)
    const int ob = (((m >> 7) << 3) + (d >> 6)) * 8192 + ((m & 127) << 6) + (d & 63);
    union { _Float16 h[2]; unsigned int u; } r, i;
    r.h[0] = (_Float16)t.x; r.h[1] = (_Float16)t.z;
    i.h[0] = (_Float16)t.y; i.h[1] = (_Float16)t.w;
    *(unsigned int*)(base + ob) = r.u;
    *(unsigned int*)(base + planeElems + ob) = i.u;
}

// ---------------------------------------------------------------------------
// Kernel 1: complex projection — round-8: CONCURRENCY fix.
// All prior variants shared grid=384 blocks on 256 CUs (1.5/CU): half the
// CUs ran one block at ~1 wave/SIMD, exposing every drain (MfmaUtil 17%).
// Now: 64x128 tile (M x E), 4 waves of 32x64, grid (64,4,3) = 768 blocks
// = exactly 3 blocks/CU; LDS single-buffered 48KB (X 16 + W 32) -> 144KB/CU.
// Structure is round-5's proven one: stage -> sync -> compute (cross-block
// overlap hides the drain). Staging: wave0 Xr+Xi, wave1 Wr, wave2 Wi
// (16 x 1KB DMA each), wave3 compute-only; source-side involution, linear
// LDS dest, ldh64 swizzled reads.
// ---------------------------------------------------------------------------
__global__ __launch_bounds__(256, 3)
void proj_kernel(const unsigned short* __restrict__ XP,
                 const unsigned short* __restrict__ WP,
                 const float2* __restrict__ bq, const float2* __restrict__ bk,
                 const float2* __restrict__ bv,
                 unsigned short* __restrict__ QG, unsigned short* __restrict__ KG,
                 unsigned short* __restrict__ VG) {
    const unsigned short* XR = XP + (size_t)blockIdx.z * 2 * PL;
    const unsigned short* XI = XR + PL;
    const unsigned short* WRp = WP + (size_t)blockIdx.z * 2 * WPL;
    const unsigned short* WIp = WRp + WPL;
    const float2* bias; unsigned short* outP;
    if (blockIdx.z == 0)      { bias = bq; outP = QG; }
    else if (blockIdx.z == 1) { bias = bk; outP = KG; }
    else                      { bias = bv; outP = VG; }
    const bool isV = (blockIdx.z == 2);

    __shared__ __align__(16) unsigned short Xs[2][64 * 64];    // [r,i][64m][64k] 16KB
    __shared__ __align__(16) unsigned short Ws[2][128 * 64];   // [r,i][128e][64k] 32KB

    const int tid  = threadIdx.x;
    const int w    = tid >> 6;
    const int lane = tid & 63;
    const int quad = lane >> 4;
    const int l15  = lane & 15;
    const int wm   = w >> 1;                 // m half (32 rows)
    const int we   = w & 1;                  // e half (64 cols)
    const int m0   = blockIdx.x * 64;
    const int e0   = blockIdx.y * 128;

    // ---- staging lane geometry (involution folded into global source) ----
    const int srow8 = lane >> 3;             // 0..7
    const int sg    = lane & 7;
    const int swz   = ((sg ^ srow8) << 3);   // source granule slot (halfs)
    // blocked-layout tile bases (elements)
    const int xbase = ((m0 >> 7) << 16) + ((m0 & 127) << 6);
    const int wbase = ((e0 >> 7) << 16);
    const unsigned short* gsX  = XR  + xbase + srow8 * 64 + swz;   // +jj>>3 ? XI
    const unsigned short* gsW0 = WRp + wbase + srow8 * 64 + swz;
    const unsigned short* gsW1 = WIp + wbase + srow8 * 64 + swz;

#define GLD(SRC, DST) __builtin_amdgcn_global_load_lds( \
        (const __attribute__((address_space(1))) void*)(SRC), \
        (__attribute__((address_space(3))) void*)(DST), 16, 0, 0)

    f32x4 Sr[2][4], Si[2][4];                // [mf][ef]
    #pragma unroll
    for (int a = 0; a < 2; ++a)
        #pragma unroll
        for (int c = 0; c < 4; ++c) { Sr[a][c] = (f32x4)0.f; Si[a][c] = (f32x4)0.f; }

    for (int s = 0; s < 8; ++s) {
        if (s) __syncthreads();              // prev compute done before overwrite
        if (w == 0) {            // X: 8 chunks Xr + 8 chunks Xi (8 rows each)
            const unsigned short* g = gsX + s * 8192;
            #pragma unroll
            for (int jj = 0; jj < 16; ++jj)
                GLD(g + (jj >> 3) * PL + (jj & 7) * 512, &Xs[jj >> 3][(jj & 7) * 512]);
        } else if (w == 1) {     // Wr: 16 chunks (128 rows)
            const unsigned short* g = gsW0 + s * 8192;
            #pragma unroll
            for (int jj = 0; jj < 16; ++jj)
                GLD(g + jj * 512, &Ws[0][jj * 512]);
        } else if (w == 2) {     // Wi: 16 chunks
            const unsigned short* g = gsW1 + s * 8192;
            #pragma unroll
            for (int jj = 0; jj < 16; ++jj)
                GLD(g + jj * 512, &Ws[1][jj * 512]);
        }
        __syncthreads();                     // vmcnt drain -> tile ready

        #pragma unroll
        for (int kc = 0; kc < 2; ++kc) {
            const int dl = kc * 32 + quad * 8;
            half8 xr[2], xi[2];
            #pragma unroll
            for (int mf = 0; mf < 2; ++mf) {
                const int mr = wm * 32 + mf * 16 + l15;
                xr[mf] = ldh64(Xs[0], mr, dl);
                xi[mf] = ldh64(Xs[1], mr, dl);
            }
            #pragma unroll
            for (int ef = 0; ef < 4; ++ef) {
                const int er = we * 64 + ef * 16 + l15;
                half8 wr  = ldh64(Ws[0], er, dl);
                half8 wi  = ldh64(Ws[1], er, dl);
                half8 wmi = negh(wi);
                #pragma unroll
                for (int mf = 0; mf < 2; ++mf) {
                    MFMA16(Sr[mf][ef], xr[mf], wr);    // Xr.Wr
                    MFMA16(Sr[mf][ef], xi[mf], wmi);   // -Xi.Wi
                    MFMA16(Si[mf][ef], xr[mf], wi);    // Xr.Wi
                    MFMA16(Si[mf][ef], xi[mf], wr);    // Xi.Wr
                }
            }
        }
    }
#undef GLD

    // ---- epilogue: + bias, fp16, write planes (V transposed) ----
    #pragma unroll
    for (int ef = 0; ef < 4; ++ef) {
        const int eg  = e0 + we * 64 + ef * 16 + l15;   // global out column
        const int hh  = eg >> 6;                         // head
        const int col = eg & 63;
        float2 bb = bias[eg];
        #pragma unroll
        for (int mf = 0; mf < 2; ++mf) {
            #pragma unroll
            for (int reg = 0; reg < 4; ++reg) {
                int m = m0 + wm * 32 + mf * 16 + quad * 4 + reg;
                int bidx = m >> 10;
                int sidx = m & 1023;
                int bh = bidx * HH + hh;
                union { _Float16 h; unsigned short u; } cr, ci;
                cr.h = (_Float16)(Sr[mf][ef][reg] + bb.x);
                ci.h = (_Float16)(Si[mf][ef][reg] + bb.y);
                size_t o = isV ? ((size_t)bh * DHD + col) * SS + sidx
                               : ((size_t)bh * SS + sidx) * DHD + col;
                outP[0 * PL + o] = cr.u;
                outP[1 * PL + o] = ci.u;
            }
        }
    }
}

// ---------------------------------------------------------------------------
// Kernel 2: fp16 MFMA flash attention, S^T formulation. (unchanged round-6/7)
// Counted-vmcnt sync (T4). Raw s_barrier + role-targeted waits.
// ---------------------------------------------------------------------------
#define AWID 72
__global__ __launch_bounds__(256, 2)
void attn_kernel(const unsigned short* __restrict__ QG, const unsigned short* __restrict__ KG,
                 const unsigned short* __restrict__ VG,
                 unsigned short* __restrict__ ObR, unsigned short* __restrict__ ObI) {
    __shared__ __align__(16) unsigned short Ks[2][2][64 * 64]; // [buf][r,i][k][d] swizzled
    __shared__ __align__(16) unsigned short Vt[2][64 * 64];    // [r,i][d][k] swizzled
    __shared__ __align__(16) unsigned short Ps[2][64 * AWID];  // [r,i][q][k]
    __shared__ float lbuf[2][2][64];                           // [plane][k-half][q]

    const int n   = blockIdx.x;
    const int bh  = (n & 7) * 4 + (n >> 7);       // XCD-local bh group
    const int q0  = ((n >> 3) & 15) * 64;
    const int b   = bh >> 3;
    const int h   = bh & 7;

    const int tid  = threadIdx.x;
    const int w    = tid >> 6;
    const int lane = tid & 63;
    const int quad = lane >> 4;
    const int l15  = lane & 15;
    const int sw   = w & 1;        // q-half (both phases)
    const int tw   = w >> 1;       // k-half (scores) / d-half (PV)

    // ---- DMA staging setup: waves 0,1 own K planes; waves 2,3 own V planes ----
    const int srow = lane >> 3;    // 0..7 (row within 8-row DMA group)
    const int sg   = lane & 7;     // dest granule; source granule = sg^srow
    const bool isK = (w < 2);
    const unsigned short* bpK = nullptr;
    const unsigned short* bpV = nullptr;
    unsigned short* ldV = nullptr;
    if (isK) {
        bpK = KG + (size_t)w * PL + (size_t)bh * SS * DHD + srow * DHD + ((sg ^ srow) << 3);
    } else {
        bpV = VG + (size_t)(w - 2) * PL + (size_t)bh * DHD * SS + srow * SS + ((sg ^ srow) << 3);
        ldV = &Vt[w - 2][0];
    }

#define GLD(SRC, DST) __builtin_amdgcn_global_load_lds( \
        (const __attribute__((address_space(1))) void*)(SRC), \
        (__attribute__((address_space(3))) void*)(DST), 16, 0, 0)

    // ---- prologue: stage K(0) into buf0 ----
    if (isK) {
        unsigned short* ld = &Ks[0][w][0];
        #pragma unroll
        for (int j = 0; j < 8; ++j) GLD(bpK + j * 8 * DHD, ld + j * 512);
    }

    // Q in B-layout registers: lane = q col, quad*8+j = d within 32-window
    half8 qfr[2][2], qfi[2][2], qfmi[2][2];       // [qt][kc]
    #pragma unroll
    for (int qt = 0; qt < 2; ++qt)
        #pragma unroll
        for (int kc = 0; kc < 2; ++kc) {
            size_t qa = ((size_t)bh * SS + q0 + sw * 32 + qt * 16 + l15) * DHD + kc * 32 + quad * 8;
            qfr[qt][kc]  = *(const half8*)(QG + qa);
            qfi[qt][kc]  = *(const half8*)(QG + PL + qa);
            qfmi[qt][kc] = negh(qfi[qt][kc]);
        }

    f32x4 acc[2][2][4];            // [qt][dt][PrVr,PrVi,PiVr,PiVi]
    #pragma unroll
    for (int qt = 0; qt < 2; ++qt)
        #pragma unroll
        for (int dt = 0; dt < 2; ++dt)
            #pragma unroll
            for (int p = 0; p < 4; ++p) acc[qt][dt][p] = (f32x4)0.f;
    float lacc[2][2] = {{0.f, 0.f}, {0.f, 0.f}};  // [qt][plane]

    constexpr float EC = 0.18033688011112042f;    // log2(e)/8

    __syncthreads();               // K(0) staged (full drain once, prologue)

    // double-buffer pointer sets (swapped per iteration; register moves only)
    const unsigned short* Kr_c = &Ks[0][0][0];
    const unsigned short* Ki_c = &Ks[0][1][0];
    const unsigned short* Kr_n = &Ks[1][0][0];
    const unsigned short* Ki_n = &Ks[1][1][0];
    unsigned short* kst_nxt = isK ? &Ks[1][w][0] : nullptr;
    unsigned short* kst_alt = isK ? &Ks[0][w][0] : nullptr;

    for (int t = 0; t < 16; ++t) {
        // ---- issue prefetch: K(t+1) -> next buf (waves 0,1); V(t) (waves 2,3)
        if (isK) {
            if (t < 15) {
                const unsigned short* g = bpK + (size_t)(t + 1) * 64 * DHD;
                #pragma unroll
                for (int j = 0; j < 8; ++j) GLD(g + j * 8 * DHD, kst_nxt + j * 512);
            }
        } else {
            const unsigned short* g = bpV + (size_t)t * 64;
            #pragma unroll
            for (int j = 0; j < 8; ++j) GLD(g + j * 8 * SS, ldV + j * 512);
        }

        // ---- scores: S^T[k32][q32] from current K buffer ----
        f32x4 Sr[2][2], Si[2][2];   // [kt2][qt]
        #pragma unroll
        for (int a = 0; a < 2; ++a)
            #pragma unroll
            for (int c = 0; c < 2; ++c) { Sr[a][c] = (f32x4)0.f; Si[a][c] = (f32x4)0.f; }
        #pragma unroll
        for (int kc = 0; kc < 2; ++kc) {
            const int dl = kc * 32 + quad * 8;
            #pragma unroll
            for (int kt2 = 0; kt2 < 2; ++kt2) {
                const int krow = tw * 32 + kt2 * 16 + l15;
                half8 akr = ldh64(Kr_c, krow, dl);
                half8 aki = ldh64(Ki_c, krow, dl);
                #pragma unroll
                for (int qt = 0; qt < 2; ++qt) {
                    MFMA16(Sr[kt2][qt], akr, qfr[qt][kc]);    // K_r . Q_r
                    MFMA16(Sr[kt2][qt], aki, qfmi[qt][kc]);   // -K_i . Q_i
                    MFMA16(Si[kt2][qt], aki, qfr[qt][kc]);    // K_i . Q_r
                    MFMA16(Si[kt2][qt], akr, qfi[qt][kc]);    // K_r . Q_i
                }
            }
        }

        // ---- exp -> P (packed b64, q-major), l partial per lane ----
        #pragma unroll
        for (int kt2 = 0; kt2 < 2; ++kt2)
            #pragma unroll
            for (int qt = 0; qt < 2; ++qt) {
                float er0 = ex2(Sr[kt2][qt][0] * EC), er1 = ex2(Sr[kt2][qt][1] * EC);
                float er2 = ex2(Sr[kt2][qt][2] * EC), er3 = ex2(Sr[kt2][qt][3] * EC);
                float ei0 = ex2(Si[kt2][qt][0] * EC), ei1 = ex2(Si[kt2][qt][1] * EC);
                float ei2 = ex2(Si[kt2][qt][2] * EC), ei3 = ex2(Si[kt2][qt][3] * EC);
                lacc[qt][0] += (er0 + er1) + (er2 + er3);
                lacc[qt][1] += (ei0 + ei1) + (ei2 + ei3);
                const int qrow = sw * 32 + qt * 16 + l15;
                const int kcol = tw * 32 + kt2 * 16 + quad * 4;
                uint2 pr, pi;
                pr.x = cvtpk(er0, er1); pr.y = cvtpk(er2, er3);
                pi.x = cvtpk(ei0, ei1); pi.y = cvtpk(ei2, ei3);
                *(uint2*)&Ps[0][qrow * AWID + kcol] = pr;
                *(uint2*)&Ps[1][qrow * AWID + kcol] = pi;
            }

        // ---- SYNC1: publish Ps (lgkm); V-waves land V(t); K prefetch stays
        //      in flight across the barrier (counted-vmcnt, T4). ----
        asm volatile("s_waitcnt lgkmcnt(0)" ::: "memory");
        if (!isK) asm volatile("s_waitcnt vmcnt(0)" ::: "memory");
        __builtin_amdgcn_s_barrier();
        asm volatile("" ::: "memory");

        // ---- PV: out tile q32 (sw) x d32 (tw), k64 accumulation ----
        #pragma unroll
        for (int kc = 0; kc < 2; ++kc) {
            half8 ap[2][2];   // [qt][plane]
            #pragma unroll
            for (int qt = 0; qt < 2; ++qt) {
                const int qrow = sw * 32 + qt * 16 + l15;
                ap[qt][0] = *(const half8*)&Ps[0][qrow * AWID + kc * 32 + quad * 8];
                ap[qt][1] = *(const half8*)&Ps[1][qrow * AWID + kc * 32 + quad * 8];
            }
            #pragma unroll
            for (int dt = 0; dt < 2; ++dt) {
                const int drow = tw * 32 + dt * 16 + l15;
                half8 bvr = ldh64(Vt[0], drow, kc * 32 + quad * 8);
                half8 bvi = ldh64(Vt[1], drow, kc * 32 + quad * 8);
                #pragma unroll
                for (int qt = 0; qt < 2; ++qt) {
                    MFMA16(acc[qt][dt][0], ap[qt][0], bvr);
                    MFMA16(acc[qt][dt][1], ap[qt][0], bvi);
                    MFMA16(acc[qt][dt][2], ap[qt][1], bvr);
                    MFMA16(acc[qt][dt][3], ap[qt][1], bvi);
                }
            }
        }

        // ---- SYNC2: K-waves land K(t+1) (published to all by the barrier);
        //      everyone done with Vt/Ps/old K buf. ----
        if (isK) asm volatile("s_waitcnt vmcnt(0)" ::: "memory");
        __builtin_amdgcn_s_barrier();
        asm volatile("" ::: "memory");

        // swap K buffers (register moves)
        const unsigned short* tr;
        tr = Kr_c; Kr_c = Kr_n; Kr_n = tr;
        tr = Ki_c; Ki_c = Ki_n; Ki_n = tr;
        unsigned short* ts = kst_nxt; kst_nxt = kst_alt; kst_alt = ts;
    }
#undef GLD

    // ---- combine l: quad-reduce (lane's k-subset -> full k-half), store ----
    #pragma unroll
    for (int qt = 0; qt < 2; ++qt)
        #pragma unroll
        for (int p = 0; p < 2; ++p) {
            float v = lacc[qt][p];
            v += __shfl_xor(v, 16);
            v += __shfl_xor(v, 32);
            if (lane < 16) lbuf[p][tw][sw * 32 + qt * 16 + lane] = v;
        }
    __syncthreads();

    // ---- epilogue: normalize, combine complex, store fp16 planes ----
    #pragma unroll
    for (int qt = 0; qt < 2; ++qt)
        #pragma unroll
        for (int reg = 0; reg < 4; ++reg) {
            const int qloc = sw * 32 + qt * 16 + quad * 4 + reg;
            const float ir = 1.f / (lbuf[0][0][qloc] + lbuf[0][1][qloc]);
            const float ii = 1.f / (lbuf[1][0][qloc] + lbuf[1][1][qloc]);
            #pragma unroll
            for (int dt = 0; dt < 2; ++dt) {
                const int d = tw * 32 + dt * 16 + l15;
                union { _Float16 h; unsigned short u; } cr, ci;
                cr.h = (_Float16)(acc[qt][dt][0][reg] * ir - acc[qt][dt][3][reg] * ii);
                ci.h = (_Float16)(acc[qt][dt][1][reg] * ir + acc[qt][dt][2][reg] * ii);
                size_t o = ((size_t)b * SS + q0 + qloc) * DD + h * DHD + d;
                ObR[o] = cr.u;
                ObI[o] = ci.u;
            }
        }
}

// ---------------------------------------------------------------------------
// Kernel 3: residual + dual LayerNorm over D (biased var, eps inside sqrt)
// ---------------------------------------------------------------------------
__global__ __launch_bounds__(256)
void ln_kernel(const unsigned short* __restrict__ OrP, const unsigned short* __restrict__ OiP,
               const float2* __restrict__ Qin,
               const float* __restrict__ gr, const float* __restrict__ br,
               const float* __restrict__ gi, const float* __restrict__ bi,
               float2* __restrict__ out) {
    const int row = blockIdx.x;           // b*S + s
    const int tid = threadIdx.x;
    const size_t base = (size_t)row * DD;
    const int e0 = 2 * tid, e1 = 2 * tid + 1;

    union { unsigned int u; _Float16 h[2]; } tr, ti;
    tr.u = *(const unsigned int*)(OrP + base + e0);
    ti.u = *(const unsigned int*)(OiP + base + e0);
    float2 r0 = Qin[base + e0];
    float2 r1 = Qin[base + e1];
    float xr0 = (float)tr.h[0] + r0.x;
    float xr1 = (float)tr.h[1] + r1.x;
    float xi0 = (float)ti.h[0] + r0.y;
    float xi1 = (float)ti.h[1] + r1.y;

    float sr = xr0 + xr1;
    float si = xi0 + xi1;
    float qr = xr0 * xr0 + xr1 * xr1;
    float qi = xi0 * xi0 + xi1 * xi1;
    #pragma unroll
    for (int off = 32; off > 0; off >>= 1) {
        sr += __shfl_down(sr, off);
        si += __shfl_down(si, off);
        qr += __shfl_down(qr, off);
        qi += __shfl_down(qi, off);
    }
    __shared__ float red[4][4];
    __shared__ float stat[4];
    int lane = tid & 63, wid = tid >> 6;
    if (lane == 0) { red[wid][0] = sr; red[wid][1] = si; red[wid][2] = qr; red[wid][3] = qi; }
    __syncthreads();
    if (tid == 0) {
        sr = red[0][0] + red[1][0] + red[2][0] + red[3][0];
        si = red[0][1] + red[1][1] + red[2][1] + red[3][1];
        qr = red[0][2] + red[1][2] + red[2][2] + red[3][2];
        qi = red[0][3] + red[1][3] + red[2][3] + red[3][3];
        float mur = sr * (1.f / DD), mui = si * (1.f / DD);
        float vr = qr * (1.f / DD) - mur * mur;
        float vi = qi * (1.f / DD) - mui * mui;
        stat[0] = mur; stat[1] = mui;
        stat[2] = rsqrtf(vr + LN_EPS); stat[3] = rsqrtf(vi + LN_EPS);
    }
    __syncthreads();
    float mur = stat[0], mui = stat[1], rsr = stat[2], rsi = stat[3];
    out[base + e0] = make_float2((xr0 - mur) * rsr * gr[e0] + br[e0],
                                 (xi0 - mui) * rsi * gi[e0] + bi[e0]);
    out[base + e1] = make_float2((xr1 - mur) * rsr * gr[e1] + br[e1],
                                 (xi1 - mui) * rsi * gi[e1] + bi[e1]);
}

// ---------------------------------------------------------------------------
extern "C" void kernel_launch(void* const* d_in, const int* in_sizes, int n_in,
                              void* d_out, int out_size, void* d_ws, size_t ws_size,
                              hipStream_t stream) {
    const float2* q  = (const float2*)d_in[0];
    const float2* k  = (const float2*)d_in[1];
    const float2* v  = (const float2*)d_in[2];
    const float2* Wq = (const float2*)d_in[3];
    const float2* bq = (const float2*)d_in[4];
    const float2* Wk = (const float2*)d_in[5];
    const float2* bk = (const float2*)d_in[6];
    const float2* Wv = (const float2*)d_in[7];
    const float2* bv = (const float2*)d_in[8];
    const float*  gr = (const float*)d_in[9];
    const float*  br = (const float*)d_in[10];
    const float*  gi = (const float*)d_in[11];
    const float*  bi = (const float*)d_in[12];

    // workspace (fp16 elements): X planes, W planes, Q/K/V planes, Ob planes
    unsigned short* XP  = (unsigned short*)d_ws;           // 3*2*PL (blocked)
    unsigned short* WP  = XP + (size_t)6 * PL;             // 3*2*WPL (blocked)
    unsigned short* QG  = WP + (size_t)6 * WPL;            // 2*PL  [BH][S][64]
    unsigned short* KG  = QG + (size_t)2 * PL;             // 2*PL  [BH][S][64]
    unsigned short* VG  = KG + (size_t)2 * PL;             // 2*PL  [BH][64][S] (transposed)
    unsigned short* ObR = VG + (size_t)2 * PL;             // PL
    unsigned short* ObI = ObR + (size_t)PL;                // PL

    cvt_kernel<<<dim3(4096, 3), 256, 0, stream>>>(q, k, v, XP, PL);
    cvt_kernel<<<dim3(512, 3), 256, 0, stream>>>(Wq, Wk, Wv, WP, WPL);
    proj_kernel<<<dim3(64, 4, 3), 256, 0, stream>>>(XP, WP, bq, bk, bv, QG, KG, VG);
    attn_kernel<<<dim3(512), 256, 0, stream>>>(QG, KG, VG, ObR, ObI);
    ln_kernel<<<dim3(BB * SS), 256, 0, stream>>>(ObR, ObI, q, gr, br, gi, bi, (float2*)d_out);
}

// Round 10
// 199.453 us; speedup vs baseline: 1.0670x; 1.0324x over previous
//
#include <hip/hip_runtime.h>
#include <math.h>

#define BB  4
#define SS  1024
#define DD  512
#define HH  8
#define DHD 64
#define PL  2097152      // elements per Q/K/V/Ob plane (also B*S*D)
#define WPL 262144       // elements per W plane

constexpr float LN_EPS = 1e-5f;

using half4 = __attribute__((ext_vector_type(4))) _Float16;
using half8 = __attribute__((ext_vector_type(8))) _Float16;
using f32x4 = __attribute__((ext_vector_type(4))) float;

__device__ __forceinline__ half8 negh(half8 a) {
    union { half8 h; unsigned int u[4]; } t;
    t.h = a;
    #pragma unroll
    for (int i = 0; i < 4; ++i) t.u[i] ^= 0x80008000u;
    return t.h;
}
// 64-wide swizzled rows (XOR (row&7)<<3, 8-half granules): conflict-free b128
__device__ __forceinline__ half8 ldh64(const unsigned short* p, int row, int col) {
    return *(const half8*)(p + row * 64 + (col ^ ((row & 7) << 3)));
}
// packed f32x2 -> f16x2 (RTZ), as raw u32
__device__ __forceinline__ unsigned int cvtpk(float a, float b) {
    union { decltype(__builtin_amdgcn_cvt_pkrtz(0.f, 0.f)) v; unsigned int u; } t;
    t.v = __builtin_amdgcn_cvt_pkrtz(a, b);
    return t.u;
}
// native v_exp_f32 (2^x) — NOT the precise OCML exp2f path
__device__ __forceinline__ float ex2(float x) { return __builtin_amdgcn_exp2f(x); }
#define MFMA16(acc, a, b) acc = __builtin_amdgcn_mfma_f32_16x16x32_f16(a, b, acc, 0, 0, 0)

// ---------------------------------------------------------------------------
// Kernel 0: fp32 complex -> fp16 r/i planes, TILE-BLOCKED layout:
// plane stored as [m/128][d/64][128][64] so proj's K-step strips are
// contiguous (HBM-stream friendly) instead of 128B-at-1KB-stride.
// ---------------------------------------------------------------------------
__global__ __launch_bounds__(256)
void cvt_kernel(const float2* __restrict__ s0, const float2* __restrict__ s1,
                const float2* __restrict__ s2, unsigned short* __restrict__ dst,
                int planeElems) {
    const int z = blockIdx.y;
    const float2* src = z == 0 ? s0 : (z == 1 ? s1 : s2);
    unsigned short* base = dst + (size_t)z * 2 * planeElems;
    const int idx = (blockIdx.x * 256 + threadIdx.x) * 2;   // complex index (even)
    float4 t = *(const float4*)(src + idx);
    const int m = idx >> 9;          // row
    const int d = idx & 511;         // col (even)
    const int ob = (((m >> 7) << 3) + (d >> 6)) * 8192 + ((m & 127) << 6) + (d & 63);
    union { _Float16 h[2]; unsigned int u; } r, i;
    r.h[0] = (_Float16)t.x; r.h[1] = (_Float16)t.z;
    i.h[0] = (_Float16)t.y; i.h[1] = (_Float16)t.w;
    *(unsigned int*)(base + ob) = r.u;
    *(unsigned int*)(base + planeElems + ob) = i.u;
}

// ---------------------------------------------------------------------------
// Kernel 1: complex projection (unchanged from round 8: 64x128 tile, 4 waves
// of 32x64, grid (64,4,3)=768 blocks = 3 blocks/CU, 48KB LDS single-buffer).
// ---------------------------------------------------------------------------
__global__ __launch_bounds__(256, 3)
void proj_kernel(const unsigned short* __restrict__ XP,
                 const unsigned short* __restrict__ WP,
                 const float2* __restrict__ bq, const float2* __restrict__ bk,
                 const float2* __restrict__ bv,
                 unsigned short* __restrict__ QG, unsigned short* __restrict__ KG,
                 unsigned short* __restrict__ VG) {
    const unsigned short* XR = XP + (size_t)blockIdx.z * 2 * PL;
    const unsigned short* XI = XR + PL;
    const unsigned short* WRp = WP + (size_t)blockIdx.z * 2 * WPL;
    const unsigned short* WIp = WRp + WPL;
    const float2* bias; unsigned short* outP;
    if (blockIdx.z == 0)      { bias = bq; outP = QG; }
    else if (blockIdx.z == 1) { bias = bk; outP = KG; }
    else                      { bias = bv; outP = VG; }
    const bool isV = (blockIdx.z == 2);

    __shared__ __align__(16) unsigned short Xs[2][64 * 64];    // [r,i][64m][64k] 16KB
    __shared__ __align__(16) unsigned short Ws[2][128 * 64];   // [r,i][128e][64k] 32KB

    const int tid  = threadIdx.x;
    const int w    = tid >> 6;
    const int lane = tid & 63;
    const int quad = lane >> 4;
    const int l15  = lane & 15;
    const int wm   = w >> 1;                 // m half (32 rows)
    const int we   = w & 1;                  // e half (64 cols)
    const int m0   = blockIdx.x * 64;
    const int e0   = blockIdx.y * 128;

    // ---- staging lane geometry (involution folded into global source) ----
    const int srow8 = lane >> 3;             // 0..7
    const int sg    = lane & 7;
    const int swz   = ((sg ^ srow8) << 3);   // source granule slot (halfs)
    // blocked-layout tile bases (elements)
    const int xbase = ((m0 >> 7) << 16) + ((m0 & 127) << 6);
    const int wbase = ((e0 >> 7) << 16);
    const unsigned short* gsX  = XR  + xbase + srow8 * 64 + swz;   // +jj>>3 ? XI
    const unsigned short* gsW0 = WRp + wbase + srow8 * 64 + swz;
    const unsigned short* gsW1 = WIp + wbase + srow8 * 64 + swz;

#define GLD(SRC, DST) __builtin_amdgcn_global_load_lds( \
        (const __attribute__((address_space(1))) void*)(SRC), \
        (__attribute__((address_space(3))) void*)(DST), 16, 0, 0)

    f32x4 Sr[2][4], Si[2][4];                // [mf][ef]
    #pragma unroll
    for (int a = 0; a < 2; ++a)
        #pragma unroll
        for (int c = 0; c < 4; ++c) { Sr[a][c] = (f32x4)0.f; Si[a][c] = (f32x4)0.f; }

    for (int s = 0; s < 8; ++s) {
        if (s) __syncthreads();              // prev compute done before overwrite
        if (w == 0) {            // X: 8 chunks Xr + 8 chunks Xi (8 rows each)
            const unsigned short* g = gsX + s * 8192;
            #pragma unroll
            for (int jj = 0; jj < 16; ++jj)
                GLD(g + (jj >> 3) * PL + (jj & 7) * 512, &Xs[jj >> 3][(jj & 7) * 512]);
        } else if (w == 1) {     // Wr: 16 chunks (128 rows)
            const unsigned short* g = gsW0 + s * 8192;
            #pragma unroll
            for (int jj = 0; jj < 16; ++jj)
                GLD(g + jj * 512, &Ws[0][jj * 512]);
        } else if (w == 2) {     // Wi: 16 chunks
            const unsigned short* g = gsW1 + s * 8192;
            #pragma unroll
            for (int jj = 0; jj < 16; ++jj)
                GLD(g + jj * 512, &Ws[1][jj * 512]);
        }
        __syncthreads();                     // vmcnt drain -> tile ready

        #pragma unroll
        for (int kc = 0; kc < 2; ++kc) {
            const int dl = kc * 32 + quad * 8;
            half8 xr[2], xi[2];
            #pragma unroll
            for (int mf = 0; mf < 2; ++mf) {
                const int mr = wm * 32 + mf * 16 + l15;
                xr[mf] = ldh64(Xs[0], mr, dl);
                xi[mf] = ldh64(Xs[1], mr, dl);
            }
            #pragma unroll
            for (int ef = 0; ef < 4; ++ef) {
                const int er = we * 64 + ef * 16 + l15;
                half8 wr  = ldh64(Ws[0], er, dl);
                half8 wi  = ldh64(Ws[1], er, dl);
                half8 wmi = negh(wi);
                #pragma unroll
                for (int mf = 0; mf < 2; ++mf) {
                    MFMA16(Sr[mf][ef], xr[mf], wr);    // Xr.Wr
                    MFMA16(Sr[mf][ef], xi[mf], wmi);   // -Xi.Wi
                    MFMA16(Si[mf][ef], xr[mf], wi);    // Xr.Wi
                    MFMA16(Si[mf][ef], xi[mf], wr);    // Xi.Wr
                }
            }
        }
    }
#undef GLD

    // ---- epilogue: + bias, fp16, write planes (V transposed) ----
    #pragma unroll
    for (int ef = 0; ef < 4; ++ef) {
        const int eg  = e0 + we * 64 + ef * 16 + l15;   // global out column
        const int hh  = eg >> 6;                         // head
        const int col = eg & 63;
        float2 bb = bias[eg];
        #pragma unroll
        for (int mf = 0; mf < 2; ++mf) {
            #pragma unroll
            for (int reg = 0; reg < 4; ++reg) {
                int m = m0 + wm * 32 + mf * 16 + quad * 4 + reg;
                int bidx = m >> 10;
                int sidx = m & 1023;
                int bh = bidx * HH + hh;
                union { _Float16 h; unsigned short u; } cr, ci;
                cr.h = (_Float16)(Sr[mf][ef][reg] + bb.x);
                ci.h = (_Float16)(Si[mf][ef][reg] + bb.y);
                size_t o = isV ? ((size_t)bh * DHD + col) * SS + sidx
                               : ((size_t)bh * SS + sidx) * DHD + col;
                outP[0 * PL + o] = cr.u;
                outP[1 * PL + o] = ci.u;
            }
        }
    }
}

// ---------------------------------------------------------------------------
// Kernel 2: fp16 MFMA flash attention — round-9/10: IN-REGISTER P (T12-analog).
// Each wave owns q16 x full-k64 x full-d64 (block q-tile still 64): P never
// crosses waves, so the Ps LDS round-trip (writes+reads+conflicts) and SYNC1
// are deleted. Scores S^T lane layout (lane&15 = q, k = kt*16+quad*4+reg) is
// converted to the PV A-fragment layout (k = kc*32+quad*8+j) by a cross-quad
// permutation: src_quad = 2*(quad&1) + (tt>>1), kt = 2kc + (quad>>1), h = tt&1
// -> 2 ds_bpermute + cndmask per u32 slot (bijection re-verified round 10).
// Sync: ONE barrier/iter. K and V^T both double-buffered (staged for t+1 at
// top of iter t, drained by vmcnt(0) before the barrier). LDS 66KB, 2 blk/CU.
// exp scale folded into Q fragments (pre-scaled by log2(e)/8).
// ---------------------------------------------------------------------------
__global__ __launch_bounds__(256, 2)
void attn_kernel(const unsigned short* __restrict__ QG, const unsigned short* __restrict__ KG,
                 const unsigned short* __restrict__ VG,
                 unsigned short* __restrict__ ObR, unsigned short* __restrict__ ObI) {
    __shared__ __align__(16) unsigned short Ks[2][2][64 * 64]; // [buf][r,i][k][d] swizzled
    __shared__ __align__(16) unsigned short Vt[2][2][64 * 64]; // [buf][r,i][d][k] swizzled
    __shared__ float lbuf[2][4][16];                           // [plane][wave][q]

    const int n   = blockIdx.x;
    const int bh  = (n & 7) * 4 + (n >> 7);       // XCD-local bh group
    const int q0  = ((n >> 3) & 15) * 64;
    const int b   = bh >> 3;
    const int h   = bh & 7;

    const int tid  = threadIdx.x;
    const int w    = tid >> 6;
    const int lane = tid & 63;
    const int quad = lane >> 4;
    const int l15  = lane & 15;

    // ---- DMA staging setup: waves 0,1 own K planes; waves 2,3 own V planes ----
    const int srow = lane >> 3;    // 0..7 (row within 8-row DMA group)
    const int sg   = lane & 7;     // dest granule; source granule = sg^srow
    const bool isK = (w < 2);
    const unsigned short* bp;
    unsigned short *ld0, *ld1;
    int jstr, ktmul;
    if (isK) {
        bp = KG + (size_t)w * PL + (size_t)bh * SS * DHD + srow * DHD + ((sg ^ srow) << 3);
        jstr = 8 * DHD; ktmul = DHD;
        ld0 = &Ks[0][w][0]; ld1 = &Ks[1][w][0];
    } else {
        bp = VG + (size_t)(w - 2) * PL + (size_t)bh * DHD * SS + srow * SS + ((sg ^ srow) << 3);
        jstr = 8 * SS; ktmul = 1;
        ld0 = &Vt[0][w - 2][0]; ld1 = &Vt[1][w - 2][0];
    }

#define GLD(SRC, DST) __builtin_amdgcn_global_load_lds( \
        (const __attribute__((address_space(1))) void*)(SRC), \
        (__attribute__((address_space(3))) void*)(DST), 16, 0, 0)

    // ---- prologue: stage K(0), V(0) into buf0 ----
    #pragma unroll
    for (int j = 0; j < 8; ++j) GLD(bp + j * jstr, ld0 + j * 512);

    // Q in B-layout registers for this wave's q16: lane&15 = q col,
    // quad*8+j = d. Pre-scaled by log2(e)/8 (folds the softmax scale).
    constexpr float EC = 0.18033688011112042f;    // log2(e)/8
    half8 qfr[2], qfi[2], qfmi[2];
    #pragma unroll
    for (int kc = 0; kc < 2; ++kc) {
        size_t qa = ((size_t)bh * SS + q0 + w * 16 + l15) * DHD + kc * 32 + quad * 8;
        half8 r = *(const half8*)(QG + qa);
        half8 i = *(const half8*)(QG + PL + qa);
        const _Float16 ech = (_Float16)EC;
        #pragma unroll
        for (int e = 0; e < 8; ++e) { r[e] *= ech; i[e] *= ech; }
        qfr[kc] = r; qfi[kc] = i; qfmi[kc] = negh(i);
    }

    f32x4 acc[4][4];               // [dt][PrVr,PrVi,PiVr,PiVi]
    #pragma unroll
    for (int dt = 0; dt < 4; ++dt)
        #pragma unroll
        for (int p = 0; p < 4; ++p) acc[dt][p] = (f32x4)0.f;
    float lacc[2] = {0.f, 0.f};    // per-plane l partial (q = l15)

    const int idx_lo = (l15 + ((quad & 1) << 5)) << 2;   // bpermute byte idx
    const int idx_hi = idx_lo + 64;

    __syncthreads();               // buf0 staged (full drain once, prologue)

    for (int t = 0; t < 16; ++t) {
        const int cur = t & 1;
        // ---- issue prefetch of t+1 into the alternate buffer ----
        if (t < 15) {
            const unsigned short* g = bp + (size_t)(t + 1) * 64 * ktmul;
            unsigned short* ld = cur ? ld0 : ld1;
            #pragma unroll
            for (int j = 0; j < 8; ++j) GLD(g + j * jstr, ld + j * 512);
        }
        const unsigned short* Krc = &Ks[cur][0][0];
        const unsigned short* Kic = &Ks[cur][1][0];
        const unsigned short* Vrc = &Vt[cur][0][0];
        const unsigned short* Vic = &Vt[cur][1][0];

        // ---- scores: S^T[k64][q16] for this wave's q16, full k64 ----
        f32x4 Sr[4], Si[4];
        #pragma unroll
        for (int kt = 0; kt < 4; ++kt) { Sr[kt] = (f32x4)0.f; Si[kt] = (f32x4)0.f; }
        #pragma unroll
        for (int kc = 0; kc < 2; ++kc) {
            const int dl = kc * 32 + quad * 8;
            #pragma unroll
            for (int kt = 0; kt < 4; ++kt) {
                half8 akr = ldh64(Krc, kt * 16 + l15, dl);
                half8 aki = ldh64(Kic, kt * 16 + l15, dl);
                MFMA16(Sr[kt], akr, qfr[kc]);     // K_r . Q_r
                MFMA16(Sr[kt], aki, qfmi[kc]);    // -K_i . Q_i
                MFMA16(Si[kt], aki, qfr[kc]);     // K_i . Q_r
                MFMA16(Si[kt], akr, qfi[kc]);     // K_r . Q_i
            }
        }

        // ---- exp (already scaled) -> packed fp16 pairs, l partials ----
        unsigned int ar[4][2], ai[4][2];          // [kt][pair]
        #pragma unroll
        for (int kt = 0; kt < 4; ++kt) {
            float er0 = ex2(Sr[kt][0]), er1 = ex2(Sr[kt][1]);
            float er2 = ex2(Sr[kt][2]), er3 = ex2(Sr[kt][3]);
            float ei0 = ex2(Si[kt][0]), ei1 = ex2(Si[kt][1]);
            float ei2 = ex2(Si[kt][2]), ei3 = ex2(Si[kt][3]);
            lacc[0] += (er0 + er1) + (er2 + er3);
            lacc[1] += (ei0 + ei1) + (ei2 + ei3);
            ar[kt][0] = cvtpk(er0, er1); ar[kt][1] = cvtpk(er2, er3);
            ai[kt][0] = cvtpk(ei0, ei1); ai[kt][1] = cvtpk(ei2, ei3);
        }

        // ---- PV with in-register P redistribution (cross-quad bpermute) ----
        #pragma unroll
        for (int kc = 0; kc < 2; ++kc) {
            union { unsigned int u[4]; half8 h; } pr_, pi_;
            #pragma unroll
            for (int tt = 0; tt < 4; ++tt) {
                const int idx = (tt >> 1) ? idx_hi : idx_lo;
                const int hh  = tt & 1;
                int rlo = __builtin_amdgcn_ds_bpermute(idx, (int)ar[2 * kc][hh]);
                int rhi = __builtin_amdgcn_ds_bpermute(idx, (int)ar[2 * kc + 1][hh]);
                int ilo = __builtin_amdgcn_ds_bpermute(idx, (int)ai[2 * kc][hh]);
                int ihi = __builtin_amdgcn_ds_bpermute(idx, (int)ai[2 * kc + 1][hh]);
                pr_.u[tt] = (quad >> 1) ? (unsigned int)rhi : (unsigned int)rlo;
                pi_.u[tt] = (quad >> 1) ? (unsigned int)ihi : (unsigned int)ilo;
            }
            #pragma unroll
            for (int dt = 0; dt < 4; ++dt) {
                half8 bvr = ldh64(Vrc, dt * 16 + l15, kc * 32 + quad * 8);
                half8 bvi = ldh64(Vic, dt * 16 + l15, kc * 32 + quad * 8);
                MFMA16(acc[dt][0], pr_.h, bvr);
                MFMA16(acc[dt][1], pr_.h, bvi);
                MFMA16(acc[dt][2], pi_.h, bvr);
                MFMA16(acc[dt][3], pi_.h, bvi);
            }
        }

        // ---- single barrier: prefetches landed + everyone done with bufs ----
        asm volatile("s_waitcnt vmcnt(0)" ::: "memory");
        __builtin_amdgcn_s_barrier();
        asm volatile("" ::: "memory");
    }
#undef GLD

    // ---- l: reduce across quads (k-subsets of same q), transpose via lbuf ----
    #pragma unroll
    for (int p = 0; p < 2; ++p) {
        float v = lacc[p];
        v += __shfl_xor(v, 16);
        v += __shfl_xor(v, 32);
        if (lane < 16) lbuf[p][w][lane] = v;
    }
    __syncthreads();

    // ---- epilogue: normalize, combine complex, store fp16 planes ----
    #pragma unroll
    for (int reg = 0; reg < 4; ++reg) {
        const int qq   = quad * 4 + reg;          // q within wave tile
        const int qloc = w * 16 + qq;             // q within block tile
        const float ir = 1.f / lbuf[0][w][qq];
        const float ii = 1.f / lbuf[1][w][qq];
        #pragma unroll
        for (int dt = 0; dt < 4; ++dt) {
            const int d = dt * 16 + l15;
            union { _Float16 h; unsigned short u; } cr, ci;
            cr.h = (_Float16)(acc[dt][0][reg] * ir - acc[dt][3][reg] * ii);
            ci.h = (_Float16)(acc[dt][1][reg] * ir + acc[dt][2][reg] * ii);
            size_t o = ((size_t)b * SS + q0 + qloc) * DD + h * DHD + d;
            ObR[o] = cr.u;
            ObI[o] = ci.u;
        }
    }
}

// ---------------------------------------------------------------------------
// Kernel 3: residual + dual LayerNorm over D (biased var, eps inside sqrt)
// ---------------------------------------------------------------------------
__global__ __launch_bounds__(256)
void ln_kernel(const unsigned short* __restrict__ OrP, const unsigned short* __restrict__ OiP,
               const float2* __restrict__ Qin,
               const float* __restrict__ gr, const float* __restrict__ br,
               const float* __restrict__ gi, const float* __restrict__ bi,
               float2* __restrict__ out) {
    const int row = blockIdx.x;           // b*S + s
    const int tid = threadIdx.x;
    const size_t base = (size_t)row * DD;
    const int e0 = 2 * tid, e1 = 2 * tid + 1;

    union { unsigned int u; _Float16 h[2]; } tr, ti;
    tr.u = *(const unsigned int*)(OrP + base + e0);
    ti.u = *(const unsigned int*)(OiP + base + e0);
    float2 r0 = Qin[base + e0];
    float2 r1 = Qin[base + e1];
    float xr0 = (float)tr.h[0] + r0.x;
    float xr1 = (float)tr.h[1] + r1.x;
    float xi0 = (float)ti.h[0] + r0.y;
    float xi1 = (float)ti.h[1] + r1.y;

    float sr = xr0 + xr1;
    float si = xi0 + xi1;
    float qr = xr0 * xr0 + xr1 * xr1;
    float qi = xi0 * xi0 + xi1 * xi1;
    #pragma unroll
    for (int off = 32; off > 0; off >>= 1) {
        sr += __shfl_down(sr, off);
        si += __shfl_down(si, off);
        qr += __shfl_down(qr, off);
        qi += __shfl_down(qi, off);
    }
    __shared__ float red[4][4];
    __shared__ float stat[4];
    int lane = tid & 63, wid = tid >> 6;
    if (lane == 0) { red[wid][0] = sr; red[wid][1] = si; red[wid][2] = qr; red[wid][3] = qi; }
    __syncthreads();
    if (tid == 0) {
        sr = red[0][0] + red[1][0] + red[2][0] + red[3][0];
        si = red[0][1] + red[1][1] + red[2][1] + red[3][1];
        qr = red[0][2] + red[1][2] + red[2][2] + red[3][2];
        qi = red[0][3] + red[1][3] + red[2][3] + red[3][3];
        float mur = sr * (1.f / DD), mui = si * (1.f / DD);
        float vr = qr * (1.f / DD) - mur * mur;
        float vi = qi * (1.f / DD) - mui * mui;
        stat[0] = mur; stat[1] = mui;
        stat[2] = rsqrtf(vr + LN_EPS); stat[3] = rsqrtf(vi + LN_EPS);
    }
    __syncthreads();
    float mur = stat[0], mui = stat[1], rsr = stat[2], rsi = stat[3];
    out[base + e0] = make_float2((xr0 - mur) * rsr * gr[e0] + br[e0],
                                 (xi0 - mui) * rsi * gi[e0] + bi[e0]);
    out[base + e1] = make_float2((xr1 - mur) * rsr * gr[e1] + br[e1],
                                 (xi1 - mui) * rsi * gi[e1] + bi[e1]);
}

// ---------------------------------------------------------------------------
extern "C" void kernel_launch(void* const* d_in, const int* in_sizes, int n_in,
                              void* d_out, int out_size, void* d_ws, size_t ws_size,
                              hipStream_t stream) {
    const float2* q  = (const float2*)d_in[0];
    const float2* k  = (const float2*)d_in[1];
    const float2* v  = (const float2*)d_in[2];
    const float2* Wq = (const float2*)d_in[3];
    const float2* bq = (const float2*)d_in[4];
    const float2* Wk = (const float2*)d_in[5];
    const float2* bk = (const float2*)d_in[6];
    const float2* Wv = (const float2*)d_in[7];
    const float2* bv = (const float2*)d_in[8];
    const float*  gr = (const float*)d_in[9];
    const float*  br = (const float*)d_in[10];
    const float*  gi = (const float*)d_in[11];
    const float*  bi = (const float*)d_in[12];

    // workspace (fp16 elements): X planes, W planes, Q/K/V planes, Ob planes
    unsigned short* XP  = (unsigned short*)d_ws;           // 3*2*PL (blocked)
    unsigned short* WP  = XP + (size_t)6 * PL;             // 3*2*WPL (blocked)
    unsigned short* QG  = WP + (size_t)6 * WPL;            // 2*PL  [BH][S][64]
    unsigned short* KG  = QG + (size_t)2 * PL;             // 2*PL  [BH][S][64]
    unsigned short* VG  = KG + (size_t)2 * PL;             // 2*PL  [BH][64][S] (transposed)
    unsigned short* ObR = VG + (size_t)2 * PL;             // PL
    unsigned short* ObI = ObR + (size_t)PL;                // PL

    cvt_kernel<<<dim3(4096, 3), 256, 0, stream>>>(q, k, v, XP, PL);
    cvt_kernel<<<dim3(512, 3), 256, 0, stream>>>(Wq, Wk, Wv, WP, WPL);
    proj_kernel<<<dim3(64, 4, 3), 256, 0, stream>>>(XP, WP, bq, bk, bv, QG, KG, VG);
    attn_kernel<<<dim3(512), 256, 0, stream>>>(QG, KG, VG, ObR, ObI);
    ln_kernel<<<dim3(BB * SS), 256, 0, stream>>>(ObR, ObI, q, gr, br, gi, bi, (float2*)d_out);
}

// Round 11
// 197.103 us; speedup vs baseline: 1.0797x; 1.0119x over previous
//
#include <hip/hip_runtime.h>
#include <math.h>

#define BB  4
#define SS  1024
#define DD  512
#define HH  8
#define DHD 64
#define PL  2097152      // elements per Q/K/V/Ob plane (also B*S*D)
#define WPL 262144       // elements per W plane

constexpr float LN_EPS = 1e-5f;

using half4 = __attribute__((ext_vector_type(4))) _Float16;
using half8 = __attribute__((ext_vector_type(8))) _Float16;
using f32x4 = __attribute__((ext_vector_type(4))) float;

__device__ __forceinline__ half8 negh(half8 a) {
    union { half8 h; unsigned int u[4]; } t;
    t.h = a;
    #pragma unroll
    for (int i = 0; i < 4; ++i) t.u[i] ^= 0x80008000u;
    return t.h;
}
// 64-wide swizzled rows (XOR (row&7)<<3, 8-half granules): conflict-free b128
__device__ __forceinline__ half8 ldh64(const unsigned short* p, int row, int col) {
    return *(const half8*)(p + row * 64 + (col ^ ((row & 7) << 3)));
}
// packed f32x2 -> f16x2 (RTZ), as raw u32
__device__ __forceinline__ unsigned int cvtpk(float a, float b) {
    union { decltype(__builtin_amdgcn_cvt_pkrtz(0.f, 0.f)) v; unsigned int u; } t;
    t.v = __builtin_amdgcn_cvt_pkrtz(a, b);
    return t.u;
}
// native v_exp_f32 (2^x) — NOT the precise OCML exp2f path
__device__ __forceinline__ float ex2(float x) { return __builtin_amdgcn_exp2f(x); }
#define MFMA16(acc, a, b) acc = __builtin_amdgcn_mfma_f32_16x16x32_f16(a, b, acc, 0, 0, 0)

// ---------------------------------------------------------------------------
// Kernel 0: fp32 complex -> fp16 r/i planes, TILE-BLOCKED layout:
// plane stored as [m/128][d/64][128][64] so proj's K-step strips are
// contiguous (HBM-stream friendly) instead of 128B-at-1KB-stride.
// ---------------------------------------------------------------------------
__global__ __launch_bounds__(256)
void cvt_kernel(const float2* __restrict__ s0, const float2* __restrict__ s1,
                const float2* __restrict__ s2, unsigned short* __restrict__ dst,
                int planeElems) {
    const int z = blockIdx.y;
    const float2* src = z == 0 ? s0 : (z == 1 ? s1 : s2);
    unsigned short* base = dst + (size_t)z * 2 * planeElems;
    const int idx = (blockIdx.x * 256 + threadIdx.x) * 2;   // complex index (even)
    float4 t = *(const float4*)(src + idx);
    const int m = idx >> 9;          // row
    const int d = idx & 511;         // col (even)
    const int ob = (((m >> 7) << 3) + (d >> 6)) * 8192 + ((m & 127) << 6) + (d & 63);
    union { _Float16 h[2]; unsigned int u; } r, i;
    r.h[0] = (_Float16)t.x; r.h[1] = (_Float16)t.z;
    i.h[0] = (_Float16)t.y; i.h[1] = (_Float16)t.w;
    *(unsigned int*)(base + ob) = r.u;
    *(unsigned int*)(base + planeElems + ob) = i.u;
}

// ---------------------------------------------------------------------------
// Kernel 1: complex projection (unchanged from round 8: 64x128 tile, 4 waves
// of 32x64, grid (64,4,3)=768 blocks = 3 blocks/CU, 48KB LDS single-buffer).
// ---------------------------------------------------------------------------
__global__ __launch_bounds__(256, 3)
void proj_kernel(const unsigned short* __restrict__ XP,
                 const unsigned short* __restrict__ WP,
                 const float2* __restrict__ bq, const float2* __restrict__ bk,
                 const float2* __restrict__ bv,
                 unsigned short* __restrict__ QG, unsigned short* __restrict__ KG,
                 unsigned short* __restrict__ VG) {
    const unsigned short* XR = XP + (size_t)blockIdx.z * 2 * PL;
    const unsigned short* XI = XR + PL;
    const unsigned short* WRp = WP + (size_t)blockIdx.z * 2 * WPL;
    const unsigned short* WIp = WRp + WPL;
    const float2* bias; unsigned short* outP;
    if (blockIdx.z == 0)      { bias = bq; outP = QG; }
    else if (blockIdx.z == 1) { bias = bk; outP = KG; }
    else                      { bias = bv; outP = VG; }
    const bool isV = (blockIdx.z == 2);

    __shared__ __align__(16) unsigned short Xs[2][64 * 64];    // [r,i][64m][64k] 16KB
    __shared__ __align__(16) unsigned short Ws[2][128 * 64];   // [r,i][128e][64k] 32KB

    const int tid  = threadIdx.x;
    const int w    = tid >> 6;
    const int lane = tid & 63;
    const int quad = lane >> 4;
    const int l15  = lane & 15;
    const int wm   = w >> 1;                 // m half (32 rows)
    const int we   = w & 1;                  // e half (64 cols)
    const int m0   = blockIdx.x * 64;
    const int e0   = blockIdx.y * 128;

    // ---- staging lane geometry (involution folded into global source) ----
    const int srow8 = lane >> 3;             // 0..7
    const int sg    = lane & 7;
    const int swz   = ((sg ^ srow8) << 3);   // source granule slot (halfs)
    // blocked-layout tile bases (elements)
    const int xbase = ((m0 >> 7) << 16) + ((m0 & 127) << 6);
    const int wbase = ((e0 >> 7) << 16);
    const unsigned short* gsX  = XR  + xbase + srow8 * 64 + swz;   // +jj>>3 ? XI
    const unsigned short* gsW0 = WRp + wbase + srow8 * 64 + swz;
    const unsigned short* gsW1 = WIp + wbase + srow8 * 64 + swz;

#define GLD(SRC, DST) __builtin_amdgcn_global_load_lds( \
        (const __attribute__((address_space(1))) void*)(SRC), \
        (__attribute__((address_space(3))) void*)(DST), 16, 0, 0)

    f32x4 Sr[2][4], Si[2][4];                // [mf][ef]
    #pragma unroll
    for (int a = 0; a < 2; ++a)
        #pragma unroll
        for (int c = 0; c < 4; ++c) { Sr[a][c] = (f32x4)0.f; Si[a][c] = (f32x4)0.f; }

    for (int s = 0; s < 8; ++s) {
        if (s) __syncthreads();              // prev compute done before overwrite
        if (w == 0) {            // X: 8 chunks Xr + 8 chunks Xi (8 rows each)
            const unsigned short* g = gsX + s * 8192;
            #pragma unroll
            for (int jj = 0; jj < 16; ++jj)
                GLD(g + (jj >> 3) * PL + (jj & 7) * 512, &Xs[jj >> 3][(jj & 7) * 512]);
        } else if (w == 1) {     // Wr: 16 chunks (128 rows)
            const unsigned short* g = gsW0 + s * 8192;
            #pragma unroll
            for (int jj = 0; jj < 16; ++jj)
                GLD(g + jj * 512, &Ws[0][jj * 512]);
        } else if (w == 2) {     // Wi: 16 chunks
            const unsigned short* g = gsW1 + s * 8192;
            #pragma unroll
            for (int jj = 0; jj < 16; ++jj)
                GLD(g + jj * 512, &Ws[1][jj * 512]);
        }
        __syncthreads();                     // vmcnt drain -> tile ready

        #pragma unroll
        for (int kc = 0; kc < 2; ++kc) {
            const int dl = kc * 32 + quad * 8;
            half8 xr[2], xi[2];
            #pragma unroll
            for (int mf = 0; mf < 2; ++mf) {
                const int mr = wm * 32 + mf * 16 + l15;
                xr[mf] = ldh64(Xs[0], mr, dl);
                xi[mf] = ldh64(Xs[1], mr, dl);
            }
            #pragma unroll
            for (int ef = 0; ef < 4; ++ef) {
                const int er = we * 64 + ef * 16 + l15;
                half8 wr  = ldh64(Ws[0], er, dl);
                half8 wi  = ldh64(Ws[1], er, dl);
                half8 wmi = negh(wi);
                #pragma unroll
                for (int mf = 0; mf < 2; ++mf) {
                    MFMA16(Sr[mf][ef], xr[mf], wr);    // Xr.Wr
                    MFMA16(Sr[mf][ef], xi[mf], wmi);   // -Xi.Wi
                    MFMA16(Si[mf][ef], xr[mf], wi);    // Xr.Wi
                    MFMA16(Si[mf][ef], xi[mf], wr);    // Xi.Wr
                }
            }
        }
    }
#undef GLD

    // ---- epilogue: + bias, fp16, write planes (V transposed) ----
    #pragma unroll
    for (int ef = 0; ef < 4; ++ef) {
        const int eg  = e0 + we * 64 + ef * 16 + l15;   // global out column
        const int hh  = eg >> 6;                         // head
        const int col = eg & 63;
        float2 bb = bias[eg];
        #pragma unroll
        for (int mf = 0; mf < 2; ++mf) {
            #pragma unroll
            for (int reg = 0; reg < 4; ++reg) {
                int m = m0 + wm * 32 + mf * 16 + quad * 4 + reg;
                int bidx = m >> 10;
                int sidx = m & 1023;
                int bh = bidx * HH + hh;
                union { _Float16 h; unsigned short u; } cr, ci;
                cr.h = (_Float16)(Sr[mf][ef][reg] + bb.x);
                ci.h = (_Float16)(Si[mf][ef][reg] + bb.y);
                size_t o = isV ? ((size_t)bh * DHD + col) * SS + sidx
                               : ((size_t)bh * SS + sidx) * DHD + col;
                outP[0 * PL + o] = cr.u;
                outP[1 * PL + o] = ci.u;
            }
        }
    }
}

// ---------------------------------------------------------------------------
// Kernel 2: fp16 MFMA flash attention — round-11: REVERT to round-8's proven
// structure (43.6 µs): Ps-based P redistribution, K double-buffered with
// counted-vmcnt SYNC1/SYNC2 (T4), V single-buffered. The r10 in-register-P
// variant regressed (serial exp->cvtpk->bpermute->MFMA chain, 2 waves/SIMD
// can't hide it). Kept from r10: softmax scale folded into Q fragments
// (removes 16 v_mul/iter; validated in r10, absmax 0.0156).
// ---------------------------------------------------------------------------
#define AWID 72
__global__ __launch_bounds__(256, 2)
void attn_kernel(const unsigned short* __restrict__ QG, const unsigned short* __restrict__ KG,
                 const unsigned short* __restrict__ VG,
                 unsigned short* __restrict__ ObR, unsigned short* __restrict__ ObI) {
    __shared__ __align__(16) unsigned short Ks[2][2][64 * 64]; // [buf][r,i][k][d] swizzled
    __shared__ __align__(16) unsigned short Vt[2][64 * 64];    // [r,i][d][k] swizzled
    __shared__ __align__(16) unsigned short Ps[2][64 * AWID];  // [r,i][q][k]
    __shared__ float lbuf[2][2][64];                           // [plane][k-half][q]

    const int n   = blockIdx.x;
    const int bh  = (n & 7) * 4 + (n >> 7);       // XCD-local bh group
    const int q0  = ((n >> 3) & 15) * 64;
    const int b   = bh >> 3;
    const int h   = bh & 7;

    const int tid  = threadIdx.x;
    const int w    = tid >> 6;
    const int lane = tid & 63;
    const int quad = lane >> 4;
    const int l15  = lane & 15;
    const int sw   = w & 1;        // q-half (both phases)
    const int tw   = w >> 1;       // k-half (scores) / d-half (PV)

    // ---- DMA staging setup: waves 0,1 own K planes; waves 2,3 own V planes ----
    const int srow = lane >> 3;    // 0..7 (row within 8-row DMA group)
    const int sg   = lane & 7;     // dest granule; source granule = sg^srow
    const bool isK = (w < 2);
    const unsigned short* bpK = nullptr;
    const unsigned short* bpV = nullptr;
    unsigned short* ldV = nullptr;
    if (isK) {
        bpK = KG + (size_t)w * PL + (size_t)bh * SS * DHD + srow * DHD + ((sg ^ srow) << 3);
    } else {
        bpV = VG + (size_t)(w - 2) * PL + (size_t)bh * DHD * SS + srow * SS + ((sg ^ srow) << 3);
        ldV = &Vt[w - 2][0];
    }

#define GLD(SRC, DST) __builtin_amdgcn_global_load_lds( \
        (const __attribute__((address_space(1))) void*)(SRC), \
        (__attribute__((address_space(3))) void*)(DST), 16, 0, 0)

    // ---- prologue: stage K(0) into buf0 ----
    if (isK) {
        unsigned short* ld = &Ks[0][w][0];
        #pragma unroll
        for (int j = 0; j < 8; ++j) GLD(bpK + j * 8 * DHD, ld + j * 512);
    }

    // Q in B-layout registers: lane = q col, quad*8+j = d within 32-window.
    // Pre-scaled by log2(e)/8: folds the softmax scale into the MFMA.
    constexpr float EC = 0.18033688011112042f;    // log2(e)/8
    half8 qfr[2][2], qfi[2][2], qfmi[2][2];       // [qt][kc]
    #pragma unroll
    for (int qt = 0; qt < 2; ++qt)
        #pragma unroll
        for (int kc = 0; kc < 2; ++kc) {
            size_t qa = ((size_t)bh * SS + q0 + sw * 32 + qt * 16 + l15) * DHD + kc * 32 + quad * 8;
            half8 r = *(const half8*)(QG + qa);
            half8 i = *(const half8*)(QG + PL + qa);
            const _Float16 ech = (_Float16)EC;
            #pragma unroll
            for (int e = 0; e < 8; ++e) { r[e] *= ech; i[e] *= ech; }
            qfr[qt][kc]  = r;
            qfi[qt][kc]  = i;
            qfmi[qt][kc] = negh(i);
        }

    f32x4 acc[2][2][4];            // [qt][dt][PrVr,PrVi,PiVr,PiVi]
    #pragma unroll
    for (int qt = 0; qt < 2; ++qt)
        #pragma unroll
        for (int dt = 0; dt < 2; ++dt)
            #pragma unroll
            for (int p = 0; p < 4; ++p) acc[qt][dt][p] = (f32x4)0.f;
    float lacc[2][2] = {{0.f, 0.f}, {0.f, 0.f}};  // [qt][plane]

    __syncthreads();               // K(0) staged (full drain once, prologue)

    // double-buffer pointer sets (swapped per iteration; register moves only)
    const unsigned short* Kr_c = &Ks[0][0][0];
    const unsigned short* Ki_c = &Ks[0][1][0];
    const unsigned short* Kr_n = &Ks[1][0][0];
    const unsigned short* Ki_n = &Ks[1][1][0];
    unsigned short* kst_nxt = isK ? &Ks[1][w][0] : nullptr;
    unsigned short* kst_alt = isK ? &Ks[0][w][0] : nullptr;

    for (int t = 0; t < 16; ++t) {
        // ---- issue prefetch: K(t+1) -> next buf (waves 0,1); V(t) (waves 2,3)
        if (isK) {
            if (t < 15) {
                const unsigned short* g = bpK + (size_t)(t + 1) * 64 * DHD;
                #pragma unroll
                for (int j = 0; j < 8; ++j) GLD(g + j * 8 * DHD, kst_nxt + j * 512);
            }
        } else {
            const unsigned short* g = bpV + (size_t)t * 64;
            #pragma unroll
            for (int j = 0; j < 8; ++j) GLD(g + j * 8 * SS, ldV + j * 512);
        }

        // ---- scores: S^T[k32][q32] from current K buffer ----
        f32x4 Sr[2][2], Si[2][2];   // [kt2][qt]
        #pragma unroll
        for (int a = 0; a < 2; ++a)
            #pragma unroll
            for (int c = 0; c < 2; ++c) { Sr[a][c] = (f32x4)0.f; Si[a][c] = (f32x4)0.f; }
        #pragma unroll
        for (int kc = 0; kc < 2; ++kc) {
            const int dl = kc * 32 + quad * 8;
            #pragma unroll
            for (int kt2 = 0; kt2 < 2; ++kt2) {
                const int krow = tw * 32 + kt2 * 16 + l15;
                half8 akr = ldh64(Kr_c, krow, dl);
                half8 aki = ldh64(Ki_c, krow, dl);
                #pragma unroll
                for (int qt = 0; qt < 2; ++qt) {
                    MFMA16(Sr[kt2][qt], akr, qfr[qt][kc]);    // K_r . Q_r
                    MFMA16(Sr[kt2][qt], aki, qfmi[qt][kc]);   // -K_i . Q_i
                    MFMA16(Si[kt2][qt], aki, qfr[qt][kc]);    // K_i . Q_r
                    MFMA16(Si[kt2][qt], akr, qfi[qt][kc]);    // K_r . Q_i
                }
            }
        }

        // ---- exp (scale pre-folded into Q) -> P (packed b64), l partials ----
        #pragma unroll
        for (int kt2 = 0; kt2 < 2; ++kt2)
            #pragma unroll
            for (int qt = 0; qt < 2; ++qt) {
                float er0 = ex2(Sr[kt2][qt][0]), er1 = ex2(Sr[kt2][qt][1]);
                float er2 = ex2(Sr[kt2][qt][2]), er3 = ex2(Sr[kt2][qt][3]);
                float ei0 = ex2(Si[kt2][qt][0]), ei1 = ex2(Si[kt2][qt][1]);
                float ei2 = ex2(Si[kt2][qt][2]), ei3 = ex2(Si[kt2][qt][3]);
                lacc[qt][0] += (er0 + er1) + (er2 + er3);
                lacc[qt][1] += (ei0 + ei1) + (ei2 + ei3);
                const int qrow = sw * 32 + qt * 16 + l15;
                const int kcol = tw * 32 + kt2 * 16 + quad * 4;
                uint2 pr, pi;
                pr.x = cvtpk(er0, er1); pr.y = cvtpk(er2, er3);
                pi.x = cvtpk(ei0, ei1); pi.y = cvtpk(ei2, ei3);
                *(uint2*)&Ps[0][qrow * AWID + kcol] = pr;
                *(uint2*)&Ps[1][qrow * AWID + kcol] = pi;
            }

        // ---- SYNC1: publish Ps (lgkm); V-waves land V(t); K prefetch stays
        //      in flight across the barrier (counted-vmcnt, T4). ----
        asm volatile("s_waitcnt lgkmcnt(0)" ::: "memory");
        if (!isK) asm volatile("s_waitcnt vmcnt(0)" ::: "memory");
        __builtin_amdgcn_s_barrier();
        asm volatile("" ::: "memory");

        // ---- PV: out tile q32 (sw) x d32 (tw), k64 accumulation ----
        #pragma unroll
        for (int kc = 0; kc < 2; ++kc) {
            half8 ap[2][2];   // [qt][plane]
            #pragma unroll
            for (int qt = 0; qt < 2; ++qt) {
                const int qrow = sw * 32 + qt * 16 + l15;
                ap[qt][0] = *(const half8*)&Ps[0][qrow * AWID + kc * 32 + quad * 8];
                ap[qt][1] = *(const half8*)&Ps[1][qrow * AWID + kc * 32 + quad * 8];
            }
            #pragma unroll
            for (int dt = 0; dt < 2; ++dt) {
                const int drow = tw * 32 + dt * 16 + l15;
                half8 bvr = ldh64(Vt[0], drow, kc * 32 + quad * 8);
                half8 bvi = ldh64(Vt[1], drow, kc * 32 + quad * 8);
                #pragma unroll
                for (int qt = 0; qt < 2; ++qt) {
                    MFMA16(acc[qt][dt][0], ap[qt][0], bvr);
                    MFMA16(acc[qt][dt][1], ap[qt][0], bvi);
                    MFMA16(acc[qt][dt][2], ap[qt][1], bvr);
                    MFMA16(acc[qt][dt][3], ap[qt][1], bvi);
                }
            }
        }

        // ---- SYNC2: K-waves land K(t+1) (published to all by the barrier);
        //      everyone done with Vt/Ps/old K buf. ----
        if (isK) asm volatile("s_waitcnt vmcnt(0)" ::: "memory");
        __builtin_amdgcn_s_barrier();
        asm volatile("" ::: "memory");

        // swap K buffers (register moves)
        const unsigned short* tr;
        tr = Kr_c; Kr_c = Kr_n; Kr_n = tr;
        tr = Ki_c; Ki_c = Ki_n; Ki_n = tr;
        unsigned short* ts = kst_nxt; kst_nxt = kst_alt; kst_alt = ts;
    }
#undef GLD

    // ---- combine l: quad-reduce (lane's k-subset -> full k-half), store ----
    #pragma unroll
    for (int qt = 0; qt < 2; ++qt)
        #pragma unroll
        for (int p = 0; p < 2; ++p) {
            float v = lacc[qt][p];
            v += __shfl_xor(v, 16);
            v += __shfl_xor(v, 32);
            if (lane < 16) lbuf[p][tw][sw * 32 + qt * 16 + lane] = v;
        }
    __syncthreads();

    // ---- epilogue: normalize, combine complex, store fp16 planes ----
    #pragma unroll
    for (int qt = 0; qt < 2; ++qt)
        #pragma unroll
        for (int reg = 0; reg < 4; ++reg) {
            const int qloc = sw * 32 + qt * 16 + quad * 4 + reg;
            const float ir = 1.f / (lbuf[0][0][qloc] + lbuf[0][1][qloc]);
            const float ii = 1.f / (lbuf[1][0][qloc] + lbuf[1][1][qloc]);
            #pragma unroll
            for (int dt = 0; dt < 2; ++dt) {
                const int d = tw * 32 + dt * 16 + l15;
                union { _Float16 h; unsigned short u; } cr, ci;
                cr.h = (_Float16)(acc[qt][dt][0][reg] * ir - acc[qt][dt][3][reg] * ii);
                ci.h = (_Float16)(acc[qt][dt][1][reg] * ir + acc[qt][dt][2][reg] * ii);
                size_t o = ((size_t)b * SS + q0 + qloc) * DD + h * DHD + d;
                ObR[o] = cr.u;
                ObI[o] = ci.u;
            }
        }
}

// ---------------------------------------------------------------------------
// Kernel 3: residual + dual LayerNorm over D (biased var, eps inside sqrt)
// ---------------------------------------------------------------------------
__global__ __launch_bounds__(256)
void ln_kernel(const unsigned short* __restrict__ OrP, const unsigned short* __restrict__ OiP,
               const float2* __restrict__ Qin,
               const float* __restrict__ gr, const float* __restrict__ br,
               const float* __restrict__ gi, const float* __restrict__ bi,
               float2* __restrict__ out) {
    const int row = blockIdx.x;           // b*S + s
    const int tid = threadIdx.x;
    const size_t base = (size_t)row * DD;
    const int e0 = 2 * tid, e1 = 2 * tid + 1;

    union { unsigned int u; _Float16 h[2]; } tr, ti;
    tr.u = *(const unsigned int*)(OrP + base + e0);
    ti.u = *(const unsigned int*)(OiP + base + e0);
    float2 r0 = Qin[base + e0];
    float2 r1 = Qin[base + e1];
    float xr0 = (float)tr.h[0] + r0.x;
    float xr1 = (float)tr.h[1] + r1.x;
    float xi0 = (float)ti.h[0] + r0.y;
    float xi1 = (float)ti.h[1] + r1.y;

    float sr = xr0 + xr1;
    float si = xi0 + xi1;
    float qr = xr0 * xr0 + xr1 * xr1;
    float qi = xi0 * xi0 + xi1 * xi1;
    #pragma unroll
    for (int off = 32; off > 0; off >>= 1) {
        sr += __shfl_down(sr, off);
        si += __shfl_down(si, off);
        qr += __shfl_down(qr, off);
        qi += __shfl_down(qi, off);
    }
    __shared__ float red[4][4];
    __shared__ float stat[4];
    int lane = tid & 63, wid = tid >> 6;
    if (lane == 0) { red[wid][0] = sr; red[wid][1] = si; red[wid][2] = qr; red[wid][3] = qi; }
    __syncthreads();
    if (tid == 0) {
        sr = red[0][0] + red[1][0] + red[2][0] + red[3][0];
        si = red[0][1] + red[1][1] + red[2][1] + red[3][1];
        qr = red[0][2] + red[1][2] + red[2][2] + red[3][2];
        qi = red[0][3] + red[1][3] + red[2][3] + red[3][3];
        float mur = sr * (1.f / DD), mui = si * (1.f / DD);
        float vr = qr * (1.f / DD) - mur * mur;
        float vi = qi * (1.f / DD) - mui * mui;
        stat[0] = mur; stat[1] = mui;
        stat[2] = rsqrtf(vr + LN_EPS); stat[3] = rsqrtf(vi + LN_EPS);
    }
    __syncthreads();
    float mur = stat[0], mui = stat[1], rsr = stat[2], rsi = stat[3];
    out[base + e0] = make_float2((xr0 - mur) * rsr * gr[e0] + br[e0],
                                 (xi0 - mui) * rsi * gi[e0] + bi[e0]);
    out[base + e1] = make_float2((xr1 - mur) * rsr * gr[e1] + br[e1],
                                 (xi1 - mui) * rsi * gi[e1] + bi[e1]);
}

// ---------------------------------------------------------------------------
extern "C" void kernel_launch(void* const* d_in, const int* in_sizes, int n_in,
                              void* d_out, int out_size, void* d_ws, size_t ws_size,
                              hipStream_t stream) {
    const float2* q  = (const float2*)d_in[0];
    const float2* k  = (const float2*)d_in[1];
    const float2* v  = (const float2*)d_in[2];
    const float2* Wq = (const float2*)d_in[3];
    const float2* bq = (const float2*)d_in[4];
    const float2* Wk = (const float2*)d_in[5];
    const float2* bk = (const float2*)d_in[6];
    const float2* Wv = (const float2*)d_in[7];
    const float2* bv = (const float2*)d_in[8];
    const float*  gr = (const float*)d_in[9];
    const float*  br = (const float*)d_in[10];
    const float*  gi = (const float*)d_in[11];
    const float*  bi = (const float*)d_in[12];

    // workspace (fp16 elements): X planes, W planes, Q/K/V planes, Ob planes
    unsigned short* XP  = (unsigned short*)d_ws;           // 3*2*PL (blocked)
    unsigned short* WP  = XP + (size_t)6 * PL;             // 3*2*WPL (blocked)
    unsigned short* QG  = WP + (size_t)6 * WPL;            // 2*PL  [BH][S][64]
    unsigned short* KG  = QG + (size_t)2 * PL;             // 2*PL  [BH][S][64]
    unsigned short* VG  = KG + (size_t)2 * PL;             // 2*PL  [BH][64][S] (transposed)
    unsigned short* ObR = VG + (size_t)2 * PL;             // PL
    unsigned short* ObI = ObR + (size_t)PL;                // PL

    cvt_kernel<<<dim3(4096, 3), 256, 0, stream>>>(q, k, v, XP, PL);
    cvt_kernel<<<dim3(512, 3), 256, 0, stream>>>(Wq, Wk, Wv, WP, WPL);
    proj_kernel<<<dim3(64, 4, 3), 256, 0, stream>>>(XP, WP, bq, bk, bv, QG, KG, VG);
    attn_kernel<<<dim3(512), 256, 0, stream>>>(QG, KG, VG, ObR, ObI);
    ln_kernel<<<dim3(BB * SS), 256, 0, stream>>>(ObR, ObI, q, gr, br, gi, bi, (float2*)d_out);
}